// Round 1
// baseline (692.365 us; speedup 1.0000x reference)
//
#include <hip/hip_runtime.h>

// ---------------------------------------------------------------------------
// HAN forward on MI355X.
// Pipeline:
//   1. proj_kernel:  h = x @ W_proj + b  (fp32 vector GEMM, 64x128 tile)
//   2. pre_kernel:   a_s/a_d per (node, head) for both relations
//   3. per relation: CSR build (count -> scan -> fill) then agg_kernel
//      (online softmax over incoming edges + weighted message + relu)
//   4. score_kernel: GEMM-shaped tanh(out_r @ k_w + k_b) . q  -> score[r]
//   5. beta_kernel:  softmax over the 2 scores
//   6. final_kernel: (b0*out0 + b1*out1) @ lin_w + lin_b
// ---------------------------------------------------------------------------

#define HID 128
#define NHEAD 8

// ---------------- GEMM: h = X[n,256] @ W[256,128] + bias ----------------
__global__ __launch_bounds__(256) void proj_kernel(
    const float* __restrict__ X, const float* __restrict__ W,
    const float* __restrict__ bias, float* __restrict__ Hd) {
  __shared__ float As[64][33];
  __shared__ float Bs[32][128];
  const int tid = threadIdx.x;
  const int tx = tid & 15;       // 16 col-groups * 8 cols
  const int ty = tid >> 4;       // 16 row-groups * 4 rows
  const size_t row0 = (size_t)blockIdx.x * 64;

  float acc[4][8];
#pragma unroll
  for (int i = 0; i < 4; ++i)
#pragma unroll
    for (int j = 0; j < 8; ++j) acc[i][j] = 0.f;

  const int ar = tid >> 2, ac = (tid & 3) * 8;
  const int br = tid >> 3, bc = (tid & 7) * 16;

  for (int k0 = 0; k0 < 256; k0 += 32) {
    const float* ap = X + (row0 + ar) * 256 + k0 + ac;
    float4 a0 = *(const float4*)ap;
    float4 a1 = *(const float4*)(ap + 4);
    const float* bp = W + (size_t)(k0 + br) * 128 + bc;
    float4 w0 = *(const float4*)bp;
    float4 w1 = *(const float4*)(bp + 4);
    float4 w2 = *(const float4*)(bp + 8);
    float4 w3 = *(const float4*)(bp + 12);
    __syncthreads();
    As[ar][ac + 0] = a0.x; As[ar][ac + 1] = a0.y; As[ar][ac + 2] = a0.z; As[ar][ac + 3] = a0.w;
    As[ar][ac + 4] = a1.x; As[ar][ac + 5] = a1.y; As[ar][ac + 6] = a1.z; As[ar][ac + 7] = a1.w;
    *(float4*)&Bs[br][bc + 0]  = w0;
    *(float4*)&Bs[br][bc + 4]  = w1;
    *(float4*)&Bs[br][bc + 8]  = w2;
    *(float4*)&Bs[br][bc + 12] = w3;
    __syncthreads();
#pragma unroll
    for (int kk = 0; kk < 32; ++kk) {
      float4 b0 = *(float4*)&Bs[kk][tx * 8];
      float4 b1 = *(float4*)&Bs[kk][tx * 8 + 4];
      float av[4];
#pragma unroll
      for (int i = 0; i < 4; ++i) av[i] = As[ty * 4 + i][kk];
#pragma unroll
      for (int i = 0; i < 4; ++i) {
        acc[i][0] += av[i] * b0.x; acc[i][1] += av[i] * b0.y;
        acc[i][2] += av[i] * b0.z; acc[i][3] += av[i] * b0.w;
        acc[i][4] += av[i] * b1.x; acc[i][5] += av[i] * b1.y;
        acc[i][6] += av[i] * b1.z; acc[i][7] += av[i] * b1.w;
      }
    }
  }
  float bv[8];
#pragma unroll
  for (int j = 0; j < 8; ++j) bv[j] = bias[tx * 8 + j];
#pragma unroll
  for (int i = 0; i < 4; ++i) {
    float* dp = Hd + (row0 + ty * 4 + i) * 128 + tx * 8;
    float4 o0 = make_float4(acc[i][0] + bv[0], acc[i][1] + bv[1], acc[i][2] + bv[2], acc[i][3] + bv[3]);
    float4 o1 = make_float4(acc[i][4] + bv[4], acc[i][5] + bv[5], acc[i][6] + bv[6], acc[i][7] + bv[7]);
    *(float4*)dp = o0;
    *(float4*)(dp + 4) = o1;
  }
}

// ---------------- per-(node,head) attention pre-products ----------------
__device__ __forceinline__ float dot16(const float4 h0, const float4 h1,
                                       const float4 h2, const float4 h3,
                                       const float* __restrict__ a) {
  float4 a0 = *(const float4*)a, a1 = *(const float4*)(a + 4);
  float4 a2 = *(const float4*)(a + 8), a3 = *(const float4*)(a + 12);
  float s = h0.x * a0.x + h0.y * a0.y + h0.z * a0.z + h0.w * a0.w;
  s += h1.x * a1.x + h1.y * a1.y + h1.z * a1.z + h1.w * a1.w;
  s += h2.x * a2.x + h2.y * a2.y + h2.z * a2.z + h2.w * a2.w;
  s += h3.x * a3.x + h3.y * a3.y + h3.z * a3.z + h3.w * a3.w;
  return s;
}

__global__ __launch_bounds__(256) void pre_kernel(
    const float* __restrict__ h,
    const float* __restrict__ att_s0, const float* __restrict__ att_d0,
    const float* __restrict__ att_s1, const float* __restrict__ att_d1,
    float* __restrict__ as0, float* __restrict__ ad0,
    float* __restrict__ as1, float* __restrict__ ad1, int n) {
  int gid = blockIdx.x * 256 + threadIdx.x;
  int node = gid >> 3, hd = gid & 7;
  if (node >= n) return;
  const float* hp = h + (size_t)node * 128 + hd * 16;
  float4 h0 = *(const float4*)hp;
  float4 h1 = *(const float4*)(hp + 4);
  float4 h2 = *(const float4*)(hp + 8);
  float4 h3 = *(const float4*)(hp + 12);
  as0[gid] = dot16(h0, h1, h2, h3, att_s0 + hd * 16);
  ad0[gid] = dot16(h0, h1, h2, h3, att_d0 + hd * 16);
  as1[gid] = dot16(h0, h1, h2, h3, att_s1 + hd * 16);
  ad1[gid] = dot16(h0, h1, h2, h3, att_d1 + hd * 16);
}

// ---------------- CSR build ----------------
__global__ void count_kernel(const int* __restrict__ dst, int* __restrict__ deg, int ne) {
  int e = blockIdx.x * 256 + threadIdx.x;
  if (e < ne) atomicAdd(&deg[dst[e]], 1);
}

__global__ __launch_bounds__(256) void scan1_kernel(
    const int* __restrict__ deg, int* __restrict__ pre, int* __restrict__ bsum, int n) {
  __shared__ int sd[256];
  int t = threadIdx.x;
  int base = blockIdx.x * 1024 + t * 4;
  int v0 = (base + 0 < n) ? deg[base + 0] : 0;
  int v1 = (base + 1 < n) ? deg[base + 1] : 0;
  int v2 = (base + 2 < n) ? deg[base + 2] : 0;
  int v3 = (base + 3 < n) ? deg[base + 3] : 0;
  int sum = v0 + v1 + v2 + v3;
  sd[t] = sum;
  __syncthreads();
  for (int off = 1; off < 256; off <<= 1) {
    int x = (t >= off) ? sd[t - off] : 0;
    __syncthreads();
    if (t >= off) sd[t] += x;
    __syncthreads();
  }
  if (t == 255) bsum[blockIdx.x] = sd[255];
  int run = sd[t] - sum;
  if (base + 0 < n) pre[base + 0] = run; run += v0;
  if (base + 1 < n) pre[base + 1] = run; run += v1;
  if (base + 2 < n) pre[base + 2] = run; run += v2;
  if (base + 3 < n) pre[base + 3] = run;
}

__global__ __launch_bounds__(256) void scan2_kernel(int* __restrict__ bsum, int nb) {
  __shared__ int sd[256];
  int t = threadIdx.x;
  int v = (t < nb) ? bsum[t] : 0;
  sd[t] = v;
  __syncthreads();
  for (int off = 1; off < 256; off <<= 1) {
    int x = (t >= off) ? sd[t - off] : 0;
    __syncthreads();
    if (t >= off) sd[t] += x;
    __syncthreads();
  }
  if (t < nb) bsum[t] = sd[t] - v;  // exclusive
}

__global__ void scan3_kernel(int* __restrict__ pre, const int* __restrict__ bsum, int n, int total) {
  int i = blockIdx.x * 256 + threadIdx.x;
  if (i < n) pre[i] += bsum[i >> 10];
  if (i == n) pre[n] = total;
}

__global__ void fill_kernel(const int* __restrict__ src, const int* __restrict__ dst,
                            const int* __restrict__ row_ptr, int* __restrict__ cursor,
                            int* __restrict__ csr_src, int ne) {
  int e = blockIdx.x * 256 + threadIdx.x;
  if (e < ne) {
    int d = dst[e];
    int slot = row_ptr[d] + atomicAdd(&cursor[d], 1);
    csr_src[slot] = src[e];
  }
}

// ---------------- per-dst online-softmax aggregation ----------------
__global__ __launch_bounds__(256) void agg_kernel(
    const int* __restrict__ row_ptr, const int* __restrict__ csr_src,
    const float* __restrict__ h, const float* __restrict__ a_s,
    const float* __restrict__ a_d, float* __restrict__ outr, int n) {
  int gid = blockIdx.x * 256 + threadIdx.x;
  int node = gid >> 5;
  int lane = gid & 31;
  if (node >= n) return;
  int head = lane >> 2;
  int beg = row_ptr[node], end = row_ptr[node + 1];
  float ad = a_d[node * 8 + head];
  float m = -3.0e38f, s = 0.f;
  float ax = 0.f, ay = 0.f, az = 0.f, aw = 0.f;
  for (int e = beg; e < end; ++e) {
    int src = csr_src[e];
    float al = a_s[src * 8 + head] + ad;
    al = (al >= 0.f) ? al : 0.2f * al;
    float nm = fmaxf(m, al);
    float sc = __expf(m - nm);
    float p = __expf(al - nm);
    s = s * sc + p;
    float4 hv = *(const float4*)(h + (size_t)src * 128 + lane * 4);
    ax = ax * sc + p * hv.x;
    ay = ay * sc + p * hv.y;
    az = az * sc + p * hv.z;
    aw = aw * sc + p * hv.w;
    m = nm;
  }
  float inv = 1.f / (s + 1e-16f);   // deg==0: acc==0 so output stays 0
  float4 o;
  o.x = fmaxf(ax * inv, 0.f);
  o.y = fmaxf(ay * inv, 0.f);
  o.z = fmaxf(az * inv, 0.f);
  o.w = fmaxf(aw * inv, 0.f);
  *(float4*)(outr + (size_t)node * 128 + lane * 4) = o;
}

// ---------------- semantic score: sum tanh(out_r @ kw + kb) . q ----------------
__global__ __launch_bounds__(256) void score_kernel(
    const float* __restrict__ A, const float* __restrict__ kw,
    const float* __restrict__ kb, const float* __restrict__ q,
    float* __restrict__ score, int rel) {
  __shared__ float As[64][33];
  __shared__ float Bs[32][128];
  __shared__ float red[256];
  const int tid = threadIdx.x;
  const int tx = tid & 15;
  const int ty = tid >> 4;
  const size_t row0 = (size_t)blockIdx.x * 64;

  float acc[4][8];
#pragma unroll
  for (int i = 0; i < 4; ++i)
#pragma unroll
    for (int j = 0; j < 8; ++j) acc[i][j] = 0.f;

  const int ar = tid >> 2, ac = (tid & 3) * 8;
  const int br = tid >> 3, bc = (tid & 7) * 16;

  for (int k0 = 0; k0 < 128; k0 += 32) {
    const float* ap = A + (row0 + ar) * 128 + k0 + ac;
    float4 a0 = *(const float4*)ap;
    float4 a1 = *(const float4*)(ap + 4);
    const float* bp = kw + (size_t)(k0 + br) * 128 + bc;
    float4 w0 = *(const float4*)bp;
    float4 w1 = *(const float4*)(bp + 4);
    float4 w2 = *(const float4*)(bp + 8);
    float4 w3 = *(const float4*)(bp + 12);
    __syncthreads();
    As[ar][ac + 0] = a0.x; As[ar][ac + 1] = a0.y; As[ar][ac + 2] = a0.z; As[ar][ac + 3] = a0.w;
    As[ar][ac + 4] = a1.x; As[ar][ac + 5] = a1.y; As[ar][ac + 6] = a1.z; As[ar][ac + 7] = a1.w;
    *(float4*)&Bs[br][bc + 0]  = w0;
    *(float4*)&Bs[br][bc + 4]  = w1;
    *(float4*)&Bs[br][bc + 8]  = w2;
    *(float4*)&Bs[br][bc + 12] = w3;
    __syncthreads();
#pragma unroll
    for (int kk = 0; kk < 32; ++kk) {
      float4 b0 = *(float4*)&Bs[kk][tx * 8];
      float4 b1 = *(float4*)&Bs[kk][tx * 8 + 4];
      float av[4];
#pragma unroll
      for (int i = 0; i < 4; ++i) av[i] = As[ty * 4 + i][kk];
#pragma unroll
      for (int i = 0; i < 4; ++i) {
        acc[i][0] += av[i] * b0.x; acc[i][1] += av[i] * b0.y;
        acc[i][2] += av[i] * b0.z; acc[i][3] += av[i] * b0.w;
        acc[i][4] += av[i] * b1.x; acc[i][5] += av[i] * b1.y;
        acc[i][6] += av[i] * b1.z; acc[i][7] += av[i] * b1.w;
      }
    }
  }
  float kbv[8], qv[8];
#pragma unroll
  for (int j = 0; j < 8; ++j) { kbv[j] = kb[tx * 8 + j]; qv[j] = q[tx * 8 + j]; }
  float part = 0.f;
#pragma unroll
  for (int i = 0; i < 4; ++i)
#pragma unroll
    for (int j = 0; j < 8; ++j) part += tanhf(acc[i][j] + kbv[j]) * qv[j];
  red[tid] = part;
  __syncthreads();
  for (int off = 128; off > 0; off >>= 1) {
    if (tid < off) red[tid] += red[tid + off];
    __syncthreads();
  }
  if (tid == 0) atomicAdd(&score[rel], red[0]);
}

__global__ void beta_kernel(float* __restrict__ sb, float invn) {
  if (threadIdx.x == 0 && blockIdx.x == 0) {
    float s0 = sb[0] * invn, s1 = sb[1] * invn;
    float m = fmaxf(s0, s1);
    float e0 = __expf(s0 - m), e1 = __expf(s1 - m);
    float d = e0 + e1;
    sb[2] = e0 / d;
    sb[3] = e1 / d;
  }
}

// ---------------- fused output: (b0*out0 + b1*out1) @ lin_w + lin_b ----------------
__global__ __launch_bounds__(256) void final_kernel(
    const float* __restrict__ o0, const float* __restrict__ o1,
    const float* __restrict__ sb, const float* __restrict__ lw,
    const float* __restrict__ lb, float* __restrict__ out, int n) {
  int gid = blockIdx.x * 256 + threadIdx.x;
  int node = gid >> 5, lane = gid & 31;
  if (node >= n) return;
  float b0 = sb[2], b1 = sb[3];
  float4 v0 = *(const float4*)(o0 + (size_t)node * 128 + lane * 4);
  float4 v1 = *(const float4*)(o1 + (size_t)node * 128 + lane * 4);
  float f[4] = {b0 * v0.x + b1 * v1.x, b0 * v0.y + b1 * v1.y,
                b0 * v0.z + b1 * v1.z, b0 * v0.w + b1 * v1.w};
  float p0 = 0.f, p1 = 0.f, p2 = 0.f;
  int c0 = lane * 4;
#pragma unroll
  for (int j = 0; j < 4; ++j) {
    const float* w = lw + (size_t)(c0 + j) * 3;
    p0 += f[j] * w[0];
    p1 += f[j] * w[1];
    p2 += f[j] * w[2];
  }
#pragma unroll
  for (int off = 16; off > 0; off >>= 1) {
    p0 += __shfl_down(p0, off, 32);
    p1 += __shfl_down(p1, off, 32);
    p2 += __shfl_down(p2, off, 32);
  }
  if (lane == 0) {
    float* d = out + (size_t)node * 3;
    d[0] = p0 + lb[0];
    d[1] = p1 + lb[1];
    d[2] = p2 + lb[2];
  }
}

extern "C" void kernel_launch(void* const* d_in, const int* in_sizes, int n_in,
                              void* d_out, int out_size, void* d_ws, size_t ws_size,
                              hipStream_t stream) {
  const float* x   = (const float*)d_in[0];
  const float* Wp  = (const float*)d_in[1];
  const float* bp  = (const float*)d_in[2];
  const float* as0 = (const float*)d_in[3];
  const float* ad0 = (const float*)d_in[4];
  const float* as1 = (const float*)d_in[5];
  const float* ad1 = (const float*)d_in[6];
  const float* q   = (const float*)d_in[7];
  const float* kw  = (const float*)d_in[8];
  const float* kb  = (const float*)d_in[9];
  const float* lw  = (const float*)d_in[10];
  const float* lb  = (const float*)d_in[11];
  const int* e0s = (const int*)d_in[12];
  const int* e0d = (const int*)d_in[13];
  const int* e1s = (const int*)d_in[14];
  const int* e1d = (const int*)d_in[15];
  const int n  = in_sizes[0] / 256;   // 200000
  const int ne = in_sizes[12];        // 500000
  float* out = (float*)d_out;

  char* ws = (char*)d_ws;
  size_t off = 0;
  auto alloc = [&](size_t b) -> char* {
    char* p = ws + off;
    off = (off + b + 255) & ~(size_t)255;
    return p;
  };
  float* h    = (float*)alloc((size_t)n * 128 * 4);
  float* pas0 = (float*)alloc((size_t)n * 8 * 4);
  float* pad0 = (float*)alloc((size_t)n * 8 * 4);
  float* pas1 = (float*)alloc((size_t)n * 8 * 4);
  float* pad1 = (float*)alloc((size_t)n * 8 * 4);
  float* out0 = (float*)alloc((size_t)n * 128 * 4);
  float* out1 = (float*)alloc((size_t)n * 128 * 4);
  int* rowp0  = (int*)alloc((size_t)(n + 1) * 4);
  int* csr0   = (int*)alloc((size_t)ne * 4);
  int* rowp1  = (int*)alloc((size_t)(n + 1) * 4);
  int* csr1   = (int*)alloc((size_t)ne * 4);
  int* deg    = (int*)alloc((size_t)n * 4);
  int* cur    = (int*)alloc((size_t)n * 4);
  int* bsum   = (int*)alloc(256 * 4);
  float* sb   = (float*)alloc(4 * 4);

  const int nblk_scan = (n + 1023) / 1024;   // 196 <= 256

  hipLaunchKernelGGL(proj_kernel, dim3(n / 64), dim3(256), 0, stream, x, Wp, bp, h);
  hipLaunchKernelGGL(pre_kernel, dim3((n * 8) / 256), dim3(256), 0, stream,
                     h, as0, ad0, as1, ad1, pas0, pad0, pas1, pad1, n);

  for (int rel = 0; rel < 2; ++rel) {
    const int* es = rel ? e1s : e0s;
    const int* ed = rel ? e1d : e0d;
    int* rowp = rel ? rowp1 : rowp0;
    int* csr  = rel ? csr1 : csr0;
    hipMemsetAsync(deg, 0, (size_t)n * 4, stream);
    hipLaunchKernelGGL(count_kernel, dim3((ne + 255) / 256), dim3(256), 0, stream, ed, deg, ne);
    hipLaunchKernelGGL(scan1_kernel, dim3(nblk_scan), dim3(256), 0, stream, deg, rowp, bsum, n);
    hipLaunchKernelGGL(scan2_kernel, dim3(1), dim3(256), 0, stream, bsum, nblk_scan);
    hipLaunchKernelGGL(scan3_kernel, dim3((n + 1 + 255) / 256), dim3(256), 0, stream, rowp, bsum, n, ne);
    hipMemsetAsync(cur, 0, (size_t)n * 4, stream);
    hipLaunchKernelGGL(fill_kernel, dim3((ne + 255) / 256), dim3(256), 0, stream, es, ed, rowp, cur, csr, ne);
    hipLaunchKernelGGL(agg_kernel, dim3((n * 32) / 256), dim3(256), 0, stream,
                       rowp, csr, h, rel ? pas1 : pas0, rel ? pad1 : pad0, rel ? out1 : out0, n);
  }

  hipMemsetAsync(sb, 0, 16, stream);
  hipLaunchKernelGGL(score_kernel, dim3(n / 64), dim3(256), 0, stream, out0, kw, kb, q, sb, 0);
  hipLaunchKernelGGL(score_kernel, dim3(n / 64), dim3(256), 0, stream, out1, kw, kb, q, sb, 1);
  hipLaunchKernelGGL(beta_kernel, dim3(1), dim3(64), 0, stream, sb, 1.0f / n);
  hipLaunchKernelGGL(final_kernel, dim3((n * 32) / 256), dim3(256), 0, stream,
                     out0, out1, sb, lw, lb, out, n);
}

// Round 2
// 483.634 us; speedup vs baseline: 1.4316x; 1.4316x over previous
//
#include <hip/hip_runtime.h>

// ---------------------------------------------------------------------------
// HAN forward on MI355X — round 2: bf16 MFMA for both GEMMs, bf16 intermediates.
//   wconv_kernel: pack W (fp32) into bf16 MFMA B-fragment order (once per call)
//   proj_mfma:    h = x @ W_proj + b   (bf16 MFMA, no LDS, B from L2)
//   pre_kernel:   a_s/a_d per (node, head), both relations (h bf16)
//   CSR build per relation, then agg_kernel (online softmax, bf16 gathers)
//   score_mfma:   sum tanh(out_r @ k_w + k_b) . q   (bf16 MFMA + epilogue)
//   beta_kernel, final_kernel (bf16 reads)
// ---------------------------------------------------------------------------

typedef __attribute__((ext_vector_type(8))) short bf16x8;
typedef __attribute__((ext_vector_type(4))) float f32x4;
typedef __attribute__((ext_vector_type(8))) unsigned short ushort8;

__device__ __forceinline__ unsigned short f2b(float f) {
  union { float f; unsigned u; } v; v.f = f;
  unsigned r = v.u + 0x7fffu + ((v.u >> 16) & 1u);
  return (unsigned short)(r >> 16);
}
__device__ __forceinline__ float b2f(unsigned short u) {
  union { unsigned u; float f; } v; v.u = ((unsigned)u) << 16;
  return v.f;
}

// ---------- pack W[K][128] fp32 -> bf16 fragment order ----------
// Wf[((kt*8+nt)*64+lane)*8+j] = bf16(W[kt*32+(lane>>4)*8+j][nt*16+(lane&15)])
__global__ __launch_bounds__(256) void wconv_kernel(
    const float* __restrict__ W, unsigned short* __restrict__ Wf, int K) {
  int t = blockIdx.x * 256 + threadIdx.x;
  int total = (K / 32) * 8 * 64;
  if (t >= total) return;
  int lane = t & 63, nt = (t >> 6) & 7, kt = t >> 9;
  int c = lane & 15, ks = lane >> 4;
  int kbase = kt * 32 + ks * 8;
  int col = nt * 16 + c;
  ushort8 o;
#pragma unroll
  for (int j = 0; j < 8; ++j) o[j] = f2b(W[(size_t)(kbase + j) * 128 + col]);
  *(ushort8*)(Wf + (size_t)t * 8) = o;
}

// ---------- h = X[n,256] @ W + bias  (bf16 MFMA, out bf16) ----------
__global__ __launch_bounds__(256) void proj_mfma(
    const float* __restrict__ X, const unsigned short* __restrict__ Wf,
    const float* __restrict__ bias, unsigned short* __restrict__ Hb, int n) {
  const int tid = threadIdx.x;
  const int wid = tid >> 6, lane = tid & 63;
  const int wm = wid >> 1, wn = wid & 1;          // 2x2 waves -> 128x128 block
  const int row0 = blockIdx.x * 128 + wm * 64;
  const int r = lane & 15, ks = lane >> 4;
  f32x4 acc[4][4] = {};

  for (int kt = 0; kt < 8; ++kt) {
    const int k = kt * 32 + ks * 8;
    bf16x8 a[4], b[4];
#pragma unroll
    for (int mi = 0; mi < 4; ++mi) {
      int row = row0 + mi * 16 + r;
      row = row < n ? row : n - 1;
      const float* p = X + (size_t)row * 256 + k;
      float4 x0 = *(const float4*)p;
      float4 x1 = *(const float4*)(p + 4);
      bf16x8 v;
      v[0] = (short)f2b(x0.x); v[1] = (short)f2b(x0.y);
      v[2] = (short)f2b(x0.z); v[3] = (short)f2b(x0.w);
      v[4] = (short)f2b(x1.x); v[5] = (short)f2b(x1.y);
      v[6] = (short)f2b(x1.z); v[7] = (short)f2b(x1.w);
      a[mi] = v;
    }
#pragma unroll
    for (int ni = 0; ni < 4; ++ni) {
      int nt = wn * 4 + ni;
      b[ni] = *(const bf16x8*)(Wf + ((size_t)(kt * 8 + nt) * 64 + lane) * 8);
    }
#pragma unroll
    for (int mi = 0; mi < 4; ++mi)
#pragma unroll
      for (int ni = 0; ni < 4; ++ni)
        acc[mi][ni] = __builtin_amdgcn_mfma_f32_16x16x32_bf16(a[mi], b[ni], acc[mi][ni], 0, 0, 0);
  }
#pragma unroll
  for (int ni = 0; ni < 4; ++ni) {
    const int col = wn * 64 + ni * 16 + r;
    const float bv = bias[col];
#pragma unroll
    for (int mi = 0; mi < 4; ++mi) {
#pragma unroll
      for (int i = 0; i < 4; ++i) {
        int row = row0 + mi * 16 + ks * 4 + i;
        if (row < n) Hb[(size_t)row * 128 + col] = f2b(acc[mi][ni][i] + bv);
      }
    }
  }
}

// ---------- per-(node,head) attention pre-products ----------
__global__ __launch_bounds__(256) void pre_kernel(
    const unsigned short* __restrict__ Hb,
    const float* __restrict__ att_s0, const float* __restrict__ att_d0,
    const float* __restrict__ att_s1, const float* __restrict__ att_d1,
    float* __restrict__ as0, float* __restrict__ ad0,
    float* __restrict__ as1, float* __restrict__ ad1, int n) {
  int gid = blockIdx.x * 256 + threadIdx.x;
  int node = gid >> 3, hd = gid & 7;
  if (node >= n) return;
  const uint4* p = (const uint4*)(Hb + (size_t)node * 128 + hd * 16);
  uint4 u0 = p[0], u1 = p[1];
  float hv[16];
  unsigned uu[8] = {u0.x, u0.y, u0.z, u0.w, u1.x, u1.y, u1.z, u1.w};
#pragma unroll
  for (int j = 0; j < 8; ++j) {
    union { unsigned u; float f; } lo, hi;
    lo.u = uu[j] << 16; hi.u = uu[j] & 0xffff0000u;
    hv[2 * j] = lo.f; hv[2 * j + 1] = hi.f;
  }
  float s0 = 0, d0 = 0, s1 = 0, d1 = 0;
  const float* a0 = att_s0 + hd * 16;
  const float* b0 = att_d0 + hd * 16;
  const float* a1 = att_s1 + hd * 16;
  const float* b1 = att_d1 + hd * 16;
#pragma unroll
  for (int j = 0; j < 16; ++j) {
    s0 += hv[j] * a0[j]; d0 += hv[j] * b0[j];
    s1 += hv[j] * a1[j]; d1 += hv[j] * b1[j];
  }
  as0[gid] = s0; ad0[gid] = d0; as1[gid] = s1; ad1[gid] = d1;
}

// ---------- CSR build ----------
__global__ void count_kernel(const int* __restrict__ dst, int* __restrict__ deg, int ne) {
  int e = blockIdx.x * 256 + threadIdx.x;
  if (e < ne) atomicAdd(&deg[dst[e]], 1);
}

__global__ __launch_bounds__(256) void scan1_kernel(
    const int* __restrict__ deg, int* __restrict__ pre, int* __restrict__ bsum, int n) {
  __shared__ int sd[256];
  int t = threadIdx.x;
  int base = blockIdx.x * 1024 + t * 4;
  int v0 = (base + 0 < n) ? deg[base + 0] : 0;
  int v1 = (base + 1 < n) ? deg[base + 1] : 0;
  int v2 = (base + 2 < n) ? deg[base + 2] : 0;
  int v3 = (base + 3 < n) ? deg[base + 3] : 0;
  int sum = v0 + v1 + v2 + v3;
  sd[t] = sum;
  __syncthreads();
  for (int off = 1; off < 256; off <<= 1) {
    int x = (t >= off) ? sd[t - off] : 0;
    __syncthreads();
    if (t >= off) sd[t] += x;
    __syncthreads();
  }
  if (t == 255) bsum[blockIdx.x] = sd[255];
  int run = sd[t] - sum;
  if (base + 0 < n) pre[base + 0] = run; run += v0;
  if (base + 1 < n) pre[base + 1] = run; run += v1;
  if (base + 2 < n) pre[base + 2] = run; run += v2;
  if (base + 3 < n) pre[base + 3] = run;
}

__global__ __launch_bounds__(256) void scan2_kernel(int* __restrict__ bsum, int nb) {
  __shared__ int sd[256];
  int t = threadIdx.x;
  int v = (t < nb) ? bsum[t] : 0;
  sd[t] = v;
  __syncthreads();
  for (int off = 1; off < 256; off <<= 1) {
    int x = (t >= off) ? sd[t - off] : 0;
    __syncthreads();
    if (t >= off) sd[t] += x;
    __syncthreads();
  }
  if (t < nb) bsum[t] = sd[t] - v;
}

__global__ void scan3_kernel(int* __restrict__ pre, const int* __restrict__ bsum, int n, int total) {
  int i = blockIdx.x * 256 + threadIdx.x;
  if (i < n) pre[i] += bsum[i >> 10];
  if (i == n) pre[n] = total;
}

__global__ void fill_kernel(const int* __restrict__ src, const int* __restrict__ dst,
                            const int* __restrict__ row_ptr, int* __restrict__ cursor,
                            int* __restrict__ csr_src, int ne) {
  int e = blockIdx.x * 256 + threadIdx.x;
  if (e < ne) {
    int d = dst[e];
    int slot = row_ptr[d] + atomicAdd(&cursor[d], 1);
    csr_src[slot] = src[e];
  }
}

// ---------- per-dst online-softmax aggregation (bf16 h, bf16 out) ----------
__global__ __launch_bounds__(256) void agg_kernel(
    const int* __restrict__ row_ptr, const int* __restrict__ csr_src,
    const unsigned short* __restrict__ Hb, const float* __restrict__ a_s,
    const float* __restrict__ a_d, unsigned short* __restrict__ outr, int n) {
  int gid = blockIdx.x * 256 + threadIdx.x;
  int node = gid >> 5;
  int lane = gid & 31;
  if (node >= n) return;
  int head = lane >> 2;
  int beg = row_ptr[node], end = row_ptr[node + 1];
  float ad = a_d[node * 8 + head];
  float m = -3.0e38f, s = 0.f;
  float ax = 0.f, ay = 0.f, az = 0.f, aw = 0.f;
  for (int e = beg; e < end; ++e) {
    int src = csr_src[e];
    float al = a_s[src * 8 + head] + ad;
    al = (al >= 0.f) ? al : 0.2f * al;
    float nm = fmaxf(m, al);
    float sc = __expf(m - nm);
    float p = __expf(al - nm);
    s = s * sc + p;
    ushort4 hv = *(const ushort4*)(Hb + (size_t)src * 128 + lane * 4);
    ax = ax * sc + p * b2f(hv.x);
    ay = ay * sc + p * b2f(hv.y);
    az = az * sc + p * b2f(hv.z);
    aw = aw * sc + p * b2f(hv.w);
    m = nm;
  }
  float inv = 1.f / (s + 1e-16f);
  ushort4 o;
  o.x = f2b(fmaxf(ax * inv, 0.f));
  o.y = f2b(fmaxf(ay * inv, 0.f));
  o.z = f2b(fmaxf(az * inv, 0.f));
  o.w = f2b(fmaxf(aw * inv, 0.f));
  *(ushort4*)(outr + (size_t)node * 128 + lane * 4) = o;
}

// ---------- semantic score: sum tanh(out_r @ kw + kb) . q  (bf16 MFMA) ----------
__global__ __launch_bounds__(256) void score_mfma(
    const unsigned short* __restrict__ A, const unsigned short* __restrict__ Kf,
    const float* __restrict__ kb, const float* __restrict__ q,
    float* __restrict__ score, int rel, int n) {
  __shared__ float red[256];
  const int tid = threadIdx.x;
  const int wid = tid >> 6, lane = tid & 63;
  const int wm = wid >> 1, wn = wid & 1;
  const int row0 = blockIdx.x * 128 + wm * 64;
  const int r = lane & 15, ks = lane >> 4;
  f32x4 acc[4][4] = {};

  for (int kt = 0; kt < 4; ++kt) {
    const int k = kt * 32 + ks * 8;
    bf16x8 a[4], b[4];
#pragma unroll
    for (int mi = 0; mi < 4; ++mi) {
      int row = row0 + mi * 16 + r;
      row = row < n ? row : n - 1;
      a[mi] = *(const bf16x8*)(A + (size_t)row * 128 + k);
    }
#pragma unroll
    for (int ni = 0; ni < 4; ++ni) {
      int nt = wn * 4 + ni;
      b[ni] = *(const bf16x8*)(Kf + ((size_t)(kt * 8 + nt) * 64 + lane) * 8);
    }
#pragma unroll
    for (int mi = 0; mi < 4; ++mi)
#pragma unroll
      for (int ni = 0; ni < 4; ++ni)
        acc[mi][ni] = __builtin_amdgcn_mfma_f32_16x16x32_bf16(a[mi], b[ni], acc[mi][ni], 0, 0, 0);
  }
  float part = 0.f;
#pragma unroll
  for (int ni = 0; ni < 4; ++ni) {
    const int col = wn * 64 + ni * 16 + r;
    const float kbv = kb[col], qv = q[col];
#pragma unroll
    for (int mi = 0; mi < 4; ++mi) {
#pragma unroll
      for (int i = 0; i < 4; ++i) {
        int row = row0 + mi * 16 + ks * 4 + i;
        if (row < n) part += tanhf(acc[mi][ni][i] + kbv) * qv;
      }
    }
  }
  red[tid] = part;
  __syncthreads();
  for (int off = 128; off > 0; off >>= 1) {
    if (tid < off) red[tid] += red[tid + off];
    __syncthreads();
  }
  if (tid == 0) atomicAdd(&score[rel], red[0]);
}

__global__ void beta_kernel(float* __restrict__ sb, float invn) {
  if (threadIdx.x == 0 && blockIdx.x == 0) {
    float s0 = sb[0] * invn, s1 = sb[1] * invn;
    float m = fmaxf(s0, s1);
    float e0 = __expf(s0 - m), e1 = __expf(s1 - m);
    float d = e0 + e1;
    sb[2] = e0 / d;
    sb[3] = e1 / d;
  }
}

// ---------- fused output: (b0*out0 + b1*out1) @ lin_w + lin_b ----------
__global__ __launch_bounds__(256) void final_kernel(
    const unsigned short* __restrict__ o0, const unsigned short* __restrict__ o1,
    const float* __restrict__ sb, const float* __restrict__ lw,
    const float* __restrict__ lb, float* __restrict__ out, int n) {
  int gid = blockIdx.x * 256 + threadIdx.x;
  int node = gid >> 5, lane = gid & 31;
  if (node >= n) return;
  float b0 = sb[2], b1 = sb[3];
  ushort4 v0 = *(const ushort4*)(o0 + (size_t)node * 128 + lane * 4);
  ushort4 v1 = *(const ushort4*)(o1 + (size_t)node * 128 + lane * 4);
  float f[4] = {b0 * b2f(v0.x) + b1 * b2f(v1.x), b0 * b2f(v0.y) + b1 * b2f(v1.y),
                b0 * b2f(v0.z) + b1 * b2f(v1.z), b0 * b2f(v0.w) + b1 * b2f(v1.w)};
  float p0 = 0.f, p1 = 0.f, p2 = 0.f;
  int c0 = lane * 4;
#pragma unroll
  for (int j = 0; j < 4; ++j) {
    const float* w = lw + (size_t)(c0 + j) * 3;
    p0 += f[j] * w[0];
    p1 += f[j] * w[1];
    p2 += f[j] * w[2];
  }
#pragma unroll
  for (int off = 16; off > 0; off >>= 1) {
    p0 += __shfl_down(p0, off, 32);
    p1 += __shfl_down(p1, off, 32);
    p2 += __shfl_down(p2, off, 32);
  }
  if (lane == 0) {
    float* d = out + (size_t)node * 3;
    d[0] = p0 + lb[0];
    d[1] = p1 + lb[1];
    d[2] = p2 + lb[2];
  }
}

extern "C" void kernel_launch(void* const* d_in, const int* in_sizes, int n_in,
                              void* d_out, int out_size, void* d_ws, size_t ws_size,
                              hipStream_t stream) {
  const float* x   = (const float*)d_in[0];
  const float* Wp  = (const float*)d_in[1];
  const float* bp  = (const float*)d_in[2];
  const float* as0 = (const float*)d_in[3];
  const float* ad0 = (const float*)d_in[4];
  const float* as1 = (const float*)d_in[5];
  const float* ad1 = (const float*)d_in[6];
  const float* q   = (const float*)d_in[7];
  const float* kw  = (const float*)d_in[8];
  const float* kb  = (const float*)d_in[9];
  const float* lw  = (const float*)d_in[10];
  const float* lb  = (const float*)d_in[11];
  const int* e0s = (const int*)d_in[12];
  const int* e0d = (const int*)d_in[13];
  const int* e1s = (const int*)d_in[14];
  const int* e1d = (const int*)d_in[15];
  const int n  = in_sizes[0] / 256;   // 200000
  const int ne = in_sizes[12];        // 500000
  float* out = (float*)d_out;

  char* ws = (char*)d_ws;
  size_t off = 0;
  auto alloc = [&](size_t b) -> char* {
    char* p = ws + off;
    off = (off + b + 255) & ~(size_t)255;
    return p;
  };
  unsigned short* h    = (unsigned short*)alloc((size_t)n * 128 * 2);
  unsigned short* out0 = (unsigned short*)alloc((size_t)n * 128 * 2);
  unsigned short* out1 = (unsigned short*)alloc((size_t)n * 128 * 2);
  float* pas0 = (float*)alloc((size_t)n * 8 * 4);
  float* pad0 = (float*)alloc((size_t)n * 8 * 4);
  float* pas1 = (float*)alloc((size_t)n * 8 * 4);
  float* pad1 = (float*)alloc((size_t)n * 8 * 4);
  int* rowp0  = (int*)alloc((size_t)(n + 1) * 4);
  int* csr0   = (int*)alloc((size_t)ne * 4);
  int* rowp1  = (int*)alloc((size_t)(n + 1) * 4);
  int* csr1   = (int*)alloc((size_t)ne * 4);
  int* deg    = (int*)alloc((size_t)n * 4);
  int* cur    = (int*)alloc((size_t)n * 4);
  int* bsum   = (int*)alloc(256 * 4);
  float* sb   = (float*)alloc(4 * 4);
  unsigned short* Wpf = (unsigned short*)alloc((size_t)(256 / 32) * 8 * 64 * 8 * 2);
  unsigned short* Kwf = (unsigned short*)alloc((size_t)(128 / 32) * 8 * 64 * 8 * 2);

  const int nblk_scan = (n + 1023) / 1024;

  hipLaunchKernelGGL(wconv_kernel, dim3(16), dim3(256), 0, stream, Wp, Wpf, 256);
  hipLaunchKernelGGL(wconv_kernel, dim3(8), dim3(256), 0, stream, kw, Kwf, 128);

  const int gproj = (n + 127) / 128;
  hipLaunchKernelGGL(proj_mfma, dim3(gproj), dim3(256), 0, stream, x, Wpf, bp, h, n);
  hipLaunchKernelGGL(pre_kernel, dim3((n * 8 + 255) / 256), dim3(256), 0, stream,
                     h, as0, ad0, as1, ad1, pas0, pad0, pas1, pad1, n);

  for (int rel = 0; rel < 2; ++rel) {
    const int* es = rel ? e1s : e0s;
    const int* ed = rel ? e1d : e0d;
    int* rowp = rel ? rowp1 : rowp0;
    int* csr  = rel ? csr1 : csr0;
    hipMemsetAsync(deg, 0, (size_t)n * 4, stream);
    hipLaunchKernelGGL(count_kernel, dim3((ne + 255) / 256), dim3(256), 0, stream, ed, deg, ne);
    hipLaunchKernelGGL(scan1_kernel, dim3(nblk_scan), dim3(256), 0, stream, deg, rowp, bsum, n);
    hipLaunchKernelGGL(scan2_kernel, dim3(1), dim3(256), 0, stream, bsum, nblk_scan);
    hipLaunchKernelGGL(scan3_kernel, dim3((n + 1 + 255) / 256), dim3(256), 0, stream, rowp, bsum, n, ne);
    hipMemsetAsync(cur, 0, (size_t)n * 4, stream);
    hipLaunchKernelGGL(fill_kernel, dim3((ne + 255) / 256), dim3(256), 0, stream, es, ed, rowp, cur, csr, ne);
    hipLaunchKernelGGL(agg_kernel, dim3((n * 32 + 255) / 256), dim3(256), 0, stream,
                       rowp, csr, h, rel ? pas1 : pas0, rel ? pad1 : pad0, rel ? out1 : out0, n);
  }

  hipMemsetAsync(sb, 0, 16, stream);
  hipLaunchKernelGGL(score_mfma, dim3(gproj), dim3(256), 0, stream, out0, Kwf, kb, q, sb, 0, n);
  hipLaunchKernelGGL(score_mfma, dim3(gproj), dim3(256), 0, stream, out1, Kwf, kb, q, sb, 1, n);
  hipLaunchKernelGGL(beta_kernel, dim3(1), dim3(64), 0, stream, sb, 1.0f / n);
  hipLaunchKernelGGL(final_kernel, dim3((n * 32 + 255) / 256), dim3(256), 0, stream,
                     out0, out1, sb, lw, lb, out, n);
}

// Round 3
// 423.475 us; speedup vs baseline: 1.6350x; 1.1421x over previous
//
#include <hip/hip_runtime.h>

// ---------------------------------------------------------------------------
// HAN forward on MI355X — round 3.
//  - proj_mfma: reg-double-buffered A, LDS C-staging (coalesced bf16 stores),
//    fused per-(node,head) attention pre-products (pre_kernel eliminated)
//  - single CSR build over both relations (deg/cur of 2n, csr of 2ne)
//  - agg2 / score2: both relations in one dispatch (grid.y = 2)
//  - one memset for deg|cur|sb
// ---------------------------------------------------------------------------

typedef __attribute__((ext_vector_type(8))) short bf16x8;
typedef __attribute__((ext_vector_type(4))) float f32x4;
typedef __attribute__((ext_vector_type(8))) unsigned short ushort8;

__device__ __forceinline__ unsigned short f2b(float f) {
  union { float f; unsigned u; } v; v.f = f;
  unsigned r = v.u + 0x7fffu + ((v.u >> 16) & 1u);
  return (unsigned short)(r >> 16);
}
__device__ __forceinline__ float b2f(unsigned short u) {
  union { unsigned u; float f; } v; v.u = ((unsigned)u) << 16;
  return v.f;
}

// ---------- pack W[K][128] fp32 -> bf16 MFMA B-fragment order (both mats) ----------
// Wf[((kt*8+nt)*64+lane)*8+j] = bf16(W[kt*32+(lane>>4)*8+j][nt*16+(lane&15)])
__global__ __launch_bounds__(256) void wconv2_kernel(
    const float* __restrict__ Wp, const float* __restrict__ kw,
    unsigned short* __restrict__ Wpf, unsigned short* __restrict__ Kwf) {
  int t = blockIdx.x * 256 + threadIdx.x;
  const float* W;
  unsigned short* Wf;
  int idx;
  if (t < 4096) { W = Wp; Wf = Wpf; idx = t; }          // K=256: 8*8*64
  else if (t < 6144) { W = kw; Wf = Kwf; idx = t - 4096; } // K=128: 4*8*64
  else return;
  int lane = idx & 63, nt = (idx >> 6) & 7, kt = idx >> 9;
  int c = lane & 15, ks = lane >> 4;
  int kbase = kt * 32 + ks * 8;
  int col = nt * 16 + c;
  ushort8 o;
#pragma unroll
  for (int j = 0; j < 8; ++j) o[j] = f2b(W[(size_t)(kbase + j) * 128 + col]);
  *(ushort8*)(Wf + (size_t)idx * 8) = o;
}

// ---------- h = X[n,256] @ W + bias (bf16 out) + fused attention pre-products ----------
__global__ __launch_bounds__(256) void proj_mfma(
    const float* __restrict__ X, const unsigned short* __restrict__ Wf,
    const float* __restrict__ bias,
    const float* __restrict__ as0v, const float* __restrict__ ad0v,
    const float* __restrict__ as1v, const float* __restrict__ ad1v,
    unsigned short* __restrict__ Hb, float* __restrict__ preb, int n) {
  __shared__ unsigned short ct[128][136];   // 34 KB, rows 272B (16B aligned)
  const int tid = threadIdx.x;
  const int wid = tid >> 6, lane = tid & 63;
  const int wm = wid >> 1, wn = wid & 1;
  const int row0 = blockIdx.x * 128;
  const int rowW = row0 + wm * 64;
  const int r = lane & 15, ks = lane >> 4;
  f32x4 acc[4][4] = {};

  const float* aptr[4];
#pragma unroll
  for (int mi = 0; mi < 4; ++mi) {
    int row = rowW + mi * 16 + r;
    row = row < n ? row : n - 1;
    aptr[mi] = X + (size_t)row * 256 + ks * 8;
  }

  float4 ra[2][4][2];
#pragma unroll
  for (int mi = 0; mi < 4; ++mi) {
    ra[0][mi][0] = *(const float4*)(aptr[mi]);
    ra[0][mi][1] = *(const float4*)(aptr[mi] + 4);
  }

#pragma unroll
  for (int kt = 0; kt < 8; ++kt) {
    const int cur = kt & 1, nxt = cur ^ 1;
    if (kt < 7) {
#pragma unroll
      for (int mi = 0; mi < 4; ++mi) {
        const float* p = aptr[mi] + (kt + 1) * 32;
        ra[nxt][mi][0] = *(const float4*)p;
        ra[nxt][mi][1] = *(const float4*)(p + 4);
      }
    }
    bf16x8 b[4];
#pragma unroll
    for (int ni = 0; ni < 4; ++ni)
      b[ni] = *(const bf16x8*)(Wf + (((size_t)(kt * 8 + wn * 4 + ni)) * 64 + lane) * 8);
    bf16x8 a[4];
#pragma unroll
    for (int mi = 0; mi < 4; ++mi) {
      float4 x0 = ra[cur][mi][0], x1 = ra[cur][mi][1];
      bf16x8 v;
      v[0] = (short)f2b(x0.x); v[1] = (short)f2b(x0.y);
      v[2] = (short)f2b(x0.z); v[3] = (short)f2b(x0.w);
      v[4] = (short)f2b(x1.x); v[5] = (short)f2b(x1.y);
      v[6] = (short)f2b(x1.z); v[7] = (short)f2b(x1.w);
      a[mi] = v;
    }
#pragma unroll
    for (int mi = 0; mi < 4; ++mi)
#pragma unroll
      for (int ni = 0; ni < 4; ++ni)
        acc[mi][ni] = __builtin_amdgcn_mfma_f32_16x16x32_bf16(a[mi], b[ni], acc[mi][ni], 0, 0, 0);
  }

  // stage C tile (with bias) into LDS as bf16
#pragma unroll
  for (int ni = 0; ni < 4; ++ni) {
    const int col = wn * 64 + ni * 16 + r;
    const float bv = bias[col];
#pragma unroll
    for (int mi = 0; mi < 4; ++mi)
#pragma unroll
      for (int i = 0; i < 4; ++i)
        ct[wm * 64 + mi * 16 + ks * 4 + i][col] = f2b(acc[mi][ni][i] + bv);
  }
  __syncthreads();

  // coalesced global store: 2 threads per row, 64 bf16 (128B) each
  {
    int row = tid >> 1, half = tid & 1;
    int grow = row0 + row;
    if (grow < n) {
      ushort8* dst = (ushort8*)(Hb + (size_t)grow * 128 + half * 64);
#pragma unroll
      for (int j = 0; j < 8; ++j) dst[j] = *(ushort8*)&ct[row][half * 64 + j * 8];
    }
  }

  // fused pre-products: a_s/a_d for both relations
  const size_t n8 = (size_t)n * 8;
  for (int rh = tid; rh < 1024; rh += 256) {
    int row = rh >> 3, head = rh & 7;
    int node = row0 + row;
    if (node < n) {
      float hv[16];
#pragma unroll
      for (int j = 0; j < 16; ++j) hv[j] = b2f(ct[row][head * 16 + j]);
      float s0 = 0, d0 = 0, s1 = 0, d1 = 0;
      const float* p0 = as0v + head * 16;
      const float* p1 = ad0v + head * 16;
      const float* p2 = as1v + head * 16;
      const float* p3 = ad1v + head * 16;
#pragma unroll
      for (int j = 0; j < 16; ++j) {
        float v = hv[j];
        s0 += v * p0[j]; d0 += v * p1[j];
        s1 += v * p2[j]; d1 += v * p3[j];
      }
      size_t idx = (size_t)node * 8 + head;
      preb[idx] = s0;
      preb[n8 + idx] = d0;
      preb[2 * n8 + idx] = s1;
      preb[3 * n8 + idx] = d1;
    }
  }
}

// ---------- CSR build (both relations in one pass) ----------
__global__ void count2_kernel(const int* __restrict__ e0d, const int* __restrict__ e1d,
                              int* __restrict__ deg, int ne, int n) {
  int e = blockIdx.x * 256 + threadIdx.x;
  if (e < ne) atomicAdd(&deg[e0d[e]], 1);
  else if (e < 2 * ne) atomicAdd(&deg[n + e1d[e - ne]], 1);
}

__global__ __launch_bounds__(256) void scan1_kernel(
    const int* __restrict__ deg, int* __restrict__ pre, int* __restrict__ bsum, int m) {
  __shared__ int sd[256];
  int t = threadIdx.x;
  int base = blockIdx.x * 2048 + t * 8;
  int v[8], sum = 0;
#pragma unroll
  for (int j = 0; j < 8; ++j) {
    v[j] = (base + j < m) ? deg[base + j] : 0;
    sum += v[j];
  }
  sd[t] = sum;
  __syncthreads();
  for (int off = 1; off < 256; off <<= 1) {
    int x = (t >= off) ? sd[t - off] : 0;
    __syncthreads();
    if (t >= off) sd[t] += x;
    __syncthreads();
  }
  if (t == 255) bsum[blockIdx.x] = sd[255];
  int run = sd[t] - sum;
#pragma unroll
  for (int j = 0; j < 8; ++j) {
    if (base + j < m) pre[base + j] = run;
    run += v[j];
  }
}

__global__ __launch_bounds__(256) void scan2_kernel(int* __restrict__ bsum, int nb) {
  __shared__ int sd[256];
  int t = threadIdx.x;
  int v = (t < nb) ? bsum[t] : 0;
  sd[t] = v;
  __syncthreads();
  for (int off = 1; off < 256; off <<= 1) {
    int x = (t >= off) ? sd[t - off] : 0;
    __syncthreads();
    if (t >= off) sd[t] += x;
    __syncthreads();
  }
  if (t < nb) bsum[t] = sd[t] - v;
}

__global__ void scan3_kernel(int* __restrict__ pre, const int* __restrict__ bsum, int m, int total) {
  int i = blockIdx.x * 256 + threadIdx.x;
  if (i < m) pre[i] += bsum[i >> 11];
  if (i == m) pre[m] = total;
}

__global__ void fill2_kernel(const int* __restrict__ e0s, const int* __restrict__ e0d,
                             const int* __restrict__ e1s, const int* __restrict__ e1d,
                             const int* __restrict__ pre, int* __restrict__ cur,
                             int* __restrict__ csr, int ne, int n) {
  int e = blockIdx.x * 256 + threadIdx.x;
  int s, idx;
  if (e < ne) { idx = e0d[e]; s = e0s[e]; }
  else if (e < 2 * ne) { idx = n + e1d[e - ne]; s = e1s[e - ne]; }
  else return;
  int slot = pre[idx] + atomicAdd(&cur[idx], 1);
  csr[slot] = s;
}

// ---------- per-dst online-softmax aggregation, both relations ----------
__global__ __launch_bounds__(256) void agg2_kernel(
    const int* __restrict__ pre, const int* __restrict__ csr,
    const unsigned short* __restrict__ Hb, const float* __restrict__ preb,
    unsigned short* __restrict__ outb, int n) {
  int rel = blockIdx.y;
  int gid = blockIdx.x * 256 + threadIdx.x;
  int node = gid >> 5;
  int lane = gid & 31;
  if (node >= n) return;
  int head = lane >> 2;
  const size_t n8 = (size_t)n * 8;
  const float* a_s = preb + (size_t)(2 * rel) * n8;
  const float* a_d = preb + (size_t)(2 * rel + 1) * n8;
  int beg = pre[rel * n + node], end = pre[rel * n + node + 1];
  float ad = a_d[(size_t)node * 8 + head];
  float m = -3.0e38f, s = 0.f;
  float ax = 0.f, ay = 0.f, az = 0.f, aw = 0.f;
  int src_c = (beg < end) ? csr[beg] : 0;
  for (int e = beg; e < end; ++e) {
    int src_n = (e + 1 < end) ? csr[e + 1] : src_c;
    float al = a_s[(size_t)src_c * 8 + head] + ad;
    ushort4 hv = *(const ushort4*)(Hb + (size_t)src_c * 128 + lane * 4);
    al = (al >= 0.f) ? al : 0.2f * al;
    float nm = fmaxf(m, al);
    float sc = __expf(m - nm);
    float p = __expf(al - nm);
    s = s * sc + p;
    ax = ax * sc + p * b2f(hv.x);
    ay = ay * sc + p * b2f(hv.y);
    az = az * sc + p * b2f(hv.z);
    aw = aw * sc + p * b2f(hv.w);
    m = nm;
    src_c = src_n;
  }
  float inv = 1.f / (s + 1e-16f);
  ushort4 o;
  o.x = f2b(fmaxf(ax * inv, 0.f));
  o.y = f2b(fmaxf(ay * inv, 0.f));
  o.z = f2b(fmaxf(az * inv, 0.f));
  o.w = f2b(fmaxf(aw * inv, 0.f));
  *(ushort4*)(outb + (size_t)rel * n * 128 + (size_t)node * 128 + lane * 4) = o;
}

// ---------- semantic score, both relations: sum tanh(out_r @ kw + kb) . q ----------
__global__ __launch_bounds__(256) void score2_mfma(
    const unsigned short* __restrict__ outb, const unsigned short* __restrict__ Kf,
    const float* __restrict__ kb, const float* __restrict__ q,
    float* __restrict__ sb, int n) {
  __shared__ float red[256];
  const int rel = blockIdx.y;
  const unsigned short* A = outb + (size_t)rel * n * 128;
  const int tid = threadIdx.x;
  const int wid = tid >> 6, lane = tid & 63;
  const int wm = wid >> 1, wn = wid & 1;
  const int row0 = blockIdx.x * 128 + wm * 64;
  const int r = lane & 15, ks = lane >> 4;
  f32x4 acc[4][4] = {};

  const unsigned short* aptr[4];
#pragma unroll
  for (int mi = 0; mi < 4; ++mi) {
    int row = row0 + mi * 16 + r;
    row = row < n ? row : n - 1;
    aptr[mi] = A + (size_t)row * 128 + ks * 8;
  }
  bf16x8 ra[2][4];
#pragma unroll
  for (int mi = 0; mi < 4; ++mi) ra[0][mi] = *(const bf16x8*)(aptr[mi]);

#pragma unroll
  for (int kt = 0; kt < 4; ++kt) {
    const int cur = kt & 1, nxt = cur ^ 1;
    if (kt < 3) {
#pragma unroll
      for (int mi = 0; mi < 4; ++mi)
        ra[nxt][mi] = *(const bf16x8*)(aptr[mi] + (kt + 1) * 32);
    }
    bf16x8 b[4];
#pragma unroll
    for (int ni = 0; ni < 4; ++ni)
      b[ni] = *(const bf16x8*)(Kf + (((size_t)(kt * 8 + wn * 4 + ni)) * 64 + lane) * 8);
#pragma unroll
    for (int mi = 0; mi < 4; ++mi)
#pragma unroll
      for (int ni = 0; ni < 4; ++ni)
        acc[mi][ni] = __builtin_amdgcn_mfma_f32_16x16x32_bf16(ra[cur][mi], b[ni], acc[mi][ni], 0, 0, 0);
  }
  float part = 0.f;
#pragma unroll
  for (int ni = 0; ni < 4; ++ni) {
    const int col = wn * 64 + ni * 16 + r;
    const float kbv = kb[col], qv = q[col];
#pragma unroll
    for (int mi = 0; mi < 4; ++mi) {
#pragma unroll
      for (int i = 0; i < 4; ++i) {
        int row = row0 + mi * 16 + ks * 4 + i;
        if (row < n) part += tanhf(acc[mi][ni][i] + kbv) * qv;
      }
    }
  }
  red[tid] = part;
  __syncthreads();
  for (int off = 128; off > 0; off >>= 1) {
    if (tid < off) red[tid] += red[tid + off];
    __syncthreads();
  }
  if (tid == 0) atomicAdd(&sb[rel], red[0]);
}

__global__ void beta_kernel(float* __restrict__ sb, float invn) {
  if (threadIdx.x == 0 && blockIdx.x == 0) {
    float s0 = sb[0] * invn, s1 = sb[1] * invn;
    float m = fmaxf(s0, s1);
    float e0 = __expf(s0 - m), e1 = __expf(s1 - m);
    float d = e0 + e1;
    sb[2] = e0 / d;
    sb[3] = e1 / d;
  }
}

// ---------- fused output: (b0*out0 + b1*out1) @ lin_w + lin_b ----------
__global__ __launch_bounds__(256) void final_kernel(
    const unsigned short* __restrict__ outb, const float* __restrict__ sb,
    const float* __restrict__ lw, const float* __restrict__ lb,
    float* __restrict__ out, int n) {
  int gid = blockIdx.x * 256 + threadIdx.x;
  int node = gid >> 5, lane = gid & 31;
  if (node >= n) return;
  float b0 = sb[2], b1 = sb[3];
  const unsigned short* o0 = outb;
  const unsigned short* o1 = outb + (size_t)n * 128;
  ushort4 v0 = *(const ushort4*)(o0 + (size_t)node * 128 + lane * 4);
  ushort4 v1 = *(const ushort4*)(o1 + (size_t)node * 128 + lane * 4);
  float f[4] = {b0 * b2f(v0.x) + b1 * b2f(v1.x), b0 * b2f(v0.y) + b1 * b2f(v1.y),
                b0 * b2f(v0.z) + b1 * b2f(v1.z), b0 * b2f(v0.w) + b1 * b2f(v1.w)};
  float p0 = 0.f, p1 = 0.f, p2 = 0.f;
  int c0 = lane * 4;
#pragma unroll
  for (int j = 0; j < 4; ++j) {
    const float* w = lw + (size_t)(c0 + j) * 3;
    p0 += f[j] * w[0];
    p1 += f[j] * w[1];
    p2 += f[j] * w[2];
  }
#pragma unroll
  for (int off = 16; off > 0; off >>= 1) {
    p0 += __shfl_down(p0, off, 32);
    p1 += __shfl_down(p1, off, 32);
    p2 += __shfl_down(p2, off, 32);
  }
  if (lane == 0) {
    float* d = out + (size_t)node * 3;
    d[0] = p0 + lb[0];
    d[1] = p1 + lb[1];
    d[2] = p2 + lb[2];
  }
}

extern "C" void kernel_launch(void* const* d_in, const int* in_sizes, int n_in,
                              void* d_out, int out_size, void* d_ws, size_t ws_size,
                              hipStream_t stream) {
  const float* x   = (const float*)d_in[0];
  const float* Wp  = (const float*)d_in[1];
  const float* bp  = (const float*)d_in[2];
  const float* as0 = (const float*)d_in[3];
  const float* ad0 = (const float*)d_in[4];
  const float* as1 = (const float*)d_in[5];
  const float* ad1 = (const float*)d_in[6];
  const float* q   = (const float*)d_in[7];
  const float* kw  = (const float*)d_in[8];
  const float* kb  = (const float*)d_in[9];
  const float* lw  = (const float*)d_in[10];
  const float* lb  = (const float*)d_in[11];
  const int* e0s = (const int*)d_in[12];
  const int* e0d = (const int*)d_in[13];
  const int* e1s = (const int*)d_in[14];
  const int* e1d = (const int*)d_in[15];
  const int n  = in_sizes[0] / 256;   // 200000
  const int ne = in_sizes[12];        // 500000
  float* out = (float*)d_out;

  char* ws = (char*)d_ws;
  size_t off = 0;
  auto alloc = [&](size_t b) -> char* {
    char* p = ws + off;
    off = (off + b + 255) & ~(size_t)255;
    return p;
  };
  unsigned short* h    = (unsigned short*)alloc((size_t)n * 128 * 2);
  unsigned short* outb = (unsigned short*)alloc((size_t)2 * n * 128 * 2);
  float* preb = (float*)alloc((size_t)4 * n * 8 * 4);
  int* pre    = (int*)alloc((size_t)(2 * n + 1) * 4);
  int* csr    = (int*)alloc((size_t)2 * ne * 4);
  // contiguous zero region: deg(2n) | cur(2n) | sb(4)
  int* deg    = (int*)alloc(((size_t)4 * n + 4) * 4);
  int* cur    = deg + 2 * n;
  float* sb   = (float*)(deg + 4 * n);
  int* bsum   = (int*)alloc(256 * 4);
  unsigned short* Wpf = (unsigned short*)alloc((size_t)4096 * 8 * 2);
  unsigned short* Kwf = (unsigned short*)alloc((size_t)2048 * 8 * 2);

  const int m = 2 * n;
  const int nblk_scan = (m + 2047) / 2048;   // 196

  hipMemsetAsync(deg, 0, ((size_t)4 * n + 4) * 4, stream);
  hipLaunchKernelGGL(wconv2_kernel, dim3(24), dim3(256), 0, stream, Wp, kw, Wpf, Kwf);

  const int gproj = (n + 127) / 128;
  hipLaunchKernelGGL(proj_mfma, dim3(gproj), dim3(256), 0, stream,
                     x, Wpf, bp, as0, ad0, as1, ad1, h, preb, n);

  hipLaunchKernelGGL(count2_kernel, dim3((2 * ne + 255) / 256), dim3(256), 0, stream,
                     e0d, e1d, deg, ne, n);
  hipLaunchKernelGGL(scan1_kernel, dim3(nblk_scan), dim3(256), 0, stream, deg, pre, bsum, m);
  hipLaunchKernelGGL(scan2_kernel, dim3(1), dim3(256), 0, stream, bsum, nblk_scan);
  hipLaunchKernelGGL(scan3_kernel, dim3((m + 1 + 255) / 256), dim3(256), 0, stream,
                     pre, bsum, m, 2 * ne);
  hipLaunchKernelGGL(fill2_kernel, dim3((2 * ne + 255) / 256), dim3(256), 0, stream,
                     e0s, e0d, e1s, e1d, pre, cur, csr, ne, n);
  hipLaunchKernelGGL(agg2_kernel, dim3((n * 32 + 255) / 256, 2), dim3(256), 0, stream,
                     pre, csr, h, preb, outb, n);

  hipLaunchKernelGGL(score2_mfma, dim3(gproj, 2), dim3(256), 0, stream, outb, Kwf, kb, q, sb, n);
  hipLaunchKernelGGL(beta_kernel, dim3(1), dim3(64), 0, stream, sb, 1.0f / n);
  hipLaunchKernelGGL(final_kernel, dim3((n * 32 + 255) / 256), dim3(256), 0, stream,
                     outb, sb, lw, lb, out, n);
}

// Round 4
// 419.191 us; speedup vs baseline: 1.6517x; 1.0102x over previous
//
#include <hip/hip_runtime.h>

// ---------------------------------------------------------------------------
// HAN forward on MI355X — round 4.
//  - proj_mfma: A prefetch depth-2 (3 reg buffers), B prefetch depth-1
//    (2 reg buffers) -> enough bytes in flight to saturate HBM;
//    LDS C-staging + fused attention pre-products kept.
//  - agg2: max-free softmax (shift-invariant, bounded logits), 2-edge unroll.
//  - score2: A+B register prefetch.
//  - single CSR build over both relations; grid.y=2 fusions kept.
// ---------------------------------------------------------------------------

typedef __attribute__((ext_vector_type(8))) short bf16x8;
typedef __attribute__((ext_vector_type(4))) float f32x4;
typedef __attribute__((ext_vector_type(8))) unsigned short ushort8;

__device__ __forceinline__ unsigned short f2b(float f) {
  union { float f; unsigned u; } v; v.f = f;
  unsigned r = v.u + 0x7fffu + ((v.u >> 16) & 1u);
  return (unsigned short)(r >> 16);
}
__device__ __forceinline__ float b2f(unsigned short u) {
  union { unsigned u; float f; } v; v.u = ((unsigned)u) << 16;
  return v.f;
}

// ---------- pack W[K][128] fp32 -> bf16 MFMA B-fragment order (both mats) ----------
__global__ __launch_bounds__(256) void wconv2_kernel(
    const float* __restrict__ Wp, const float* __restrict__ kw,
    unsigned short* __restrict__ Wpf, unsigned short* __restrict__ Kwf) {
  int t = blockIdx.x * 256 + threadIdx.x;
  const float* W;
  unsigned short* Wf;
  int idx;
  if (t < 4096) { W = Wp; Wf = Wpf; idx = t; }
  else if (t < 6144) { W = kw; Wf = Kwf; idx = t - 4096; }
  else return;
  int lane = idx & 63, nt = (idx >> 6) & 7, kt = idx >> 9;
  int c = lane & 15, ks = lane >> 4;
  int kbase = kt * 32 + ks * 8;
  int col = nt * 16 + c;
  ushort8 o;
#pragma unroll
  for (int j = 0; j < 8; ++j) o[j] = f2b(W[(size_t)(kbase + j) * 128 + col]);
  *(ushort8*)(Wf + (size_t)idx * 8) = o;
}

// ---------- h = X[n,256] @ W + bias (bf16 out) + fused attention pre-products ----------
__global__ __launch_bounds__(256) void proj_mfma(
    const float* __restrict__ X, const unsigned short* __restrict__ Wf,
    const float* __restrict__ bias,
    const float* __restrict__ as0v, const float* __restrict__ ad0v,
    const float* __restrict__ as1v, const float* __restrict__ ad1v,
    unsigned short* __restrict__ Hb, float* __restrict__ preb, int n) {
  __shared__ unsigned short ct[128][136];
  const int tid = threadIdx.x;
  const int wid = tid >> 6, lane = tid & 63;
  const int wm = wid >> 1, wn = wid & 1;
  const int row0 = blockIdx.x * 128;
  const int rowW = row0 + wm * 64;
  const int r = lane & 15, ks = lane >> 4;
  f32x4 acc[4][4] = {};

  const float* aptr[4];
#pragma unroll
  for (int mi = 0; mi < 4; ++mi) {
    int row = rowW + mi * 16 + r;
    row = row < n ? row : n - 1;
    aptr[mi] = X + (size_t)row * 256 + ks * 8;
  }
  const unsigned short* bptr = Wf + ((size_t)(wn * 4) * 64 + lane) * 8;

  float4 ra[3][4][2];   // A: 3 buffers, issue kt+2 ahead
  bf16x8 rb[2][4];      // B: 2 buffers, issue kt+1 ahead

#pragma unroll
  for (int mi = 0; mi < 4; ++mi) {
    ra[0][mi][0] = *(const float4*)(aptr[mi]);
    ra[0][mi][1] = *(const float4*)(aptr[mi] + 4);
    ra[1][mi][0] = *(const float4*)(aptr[mi] + 32);
    ra[1][mi][1] = *(const float4*)(aptr[mi] + 36);
  }
#pragma unroll
  for (int ni = 0; ni < 4; ++ni)
    rb[0][ni] = *(const bf16x8*)(bptr + (size_t)ni * 64 * 8);

#pragma unroll
  for (int kt = 0; kt < 8; ++kt) {
    const int cur3 = kt % 3;
    if (kt < 6) {
      const int nx3 = (kt + 2) % 3;
#pragma unroll
      for (int mi = 0; mi < 4; ++mi) {
        const float* p = aptr[mi] + (kt + 2) * 32;
        ra[nx3][mi][0] = *(const float4*)p;
        ra[nx3][mi][1] = *(const float4*)(p + 4);
      }
    }
    if (kt < 7) {
      const int nb = (kt + 1) & 1;
      const unsigned short* bp = bptr + (size_t)(kt + 1) * 8 * 64 * 8;
#pragma unroll
      for (int ni = 0; ni < 4; ++ni)
        rb[nb][ni] = *(const bf16x8*)(bp + (size_t)ni * 64 * 8);
    }
    bf16x8 a[4];
#pragma unroll
    for (int mi = 0; mi < 4; ++mi) {
      float4 x0 = ra[cur3][mi][0], x1 = ra[cur3][mi][1];
      bf16x8 v;
      v[0] = (short)f2b(x0.x); v[1] = (short)f2b(x0.y);
      v[2] = (short)f2b(x0.z); v[3] = (short)f2b(x0.w);
      v[4] = (short)f2b(x1.x); v[5] = (short)f2b(x1.y);
      v[6] = (short)f2b(x1.z); v[7] = (short)f2b(x1.w);
      a[mi] = v;
    }
    const int cb = kt & 1;
#pragma unroll
    for (int mi = 0; mi < 4; ++mi)
#pragma unroll
      for (int ni = 0; ni < 4; ++ni)
        acc[mi][ni] = __builtin_amdgcn_mfma_f32_16x16x32_bf16(a[mi], rb[cb][ni], acc[mi][ni], 0, 0, 0);
  }

  // stage C tile (with bias) into LDS as bf16
#pragma unroll
  for (int ni = 0; ni < 4; ++ni) {
    const int col = wn * 64 + ni * 16 + r;
    const float bv = bias[col];
#pragma unroll
    for (int mi = 0; mi < 4; ++mi)
#pragma unroll
      for (int i = 0; i < 4; ++i)
        ct[wm * 64 + mi * 16 + ks * 4 + i][col] = f2b(acc[mi][ni][i] + bv);
  }
  __syncthreads();

  // coalesced global store: 2 threads per row, 128B each
  {
    int row = tid >> 1, half = tid & 1;
    int grow = row0 + row;
    if (grow < n) {
      ushort8* dst = (ushort8*)(Hb + (size_t)grow * 128 + half * 64);
#pragma unroll
      for (int j = 0; j < 8; ++j) dst[j] = *(ushort8*)&ct[row][half * 64 + j * 8];
    }
  }

  // fused pre-products
  const size_t n8 = (size_t)n * 8;
  for (int rh = tid; rh < 1024; rh += 256) {
    int row = rh >> 3, head = rh & 7;
    int node = row0 + row;
    if (node < n) {
      float hv[16];
#pragma unroll
      for (int j = 0; j < 16; ++j) hv[j] = b2f(ct[row][head * 16 + j]);
      float s0 = 0, d0 = 0, s1 = 0, d1 = 0;
      const float* p0 = as0v + head * 16;
      const float* p1 = ad0v + head * 16;
      const float* p2 = as1v + head * 16;
      const float* p3 = ad1v + head * 16;
#pragma unroll
      for (int j = 0; j < 16; ++j) {
        float v = hv[j];
        s0 += v * p0[j]; d0 += v * p1[j];
        s1 += v * p2[j]; d1 += v * p3[j];
      }
      size_t idx = (size_t)node * 8 + head;
      preb[idx] = s0;
      preb[n8 + idx] = d0;
      preb[2 * n8 + idx] = s1;
      preb[3 * n8 + idx] = d1;
    }
  }
}

// ---------- CSR build (both relations in one pass) ----------
__global__ void count2_kernel(const int* __restrict__ e0d, const int* __restrict__ e1d,
                              int* __restrict__ deg, int ne, int n) {
  int e = blockIdx.x * 256 + threadIdx.x;
  if (e < ne) atomicAdd(&deg[e0d[e]], 1);
  else if (e < 2 * ne) atomicAdd(&deg[n + e1d[e - ne]], 1);
}

__global__ __launch_bounds__(256) void scan1_kernel(
    const int* __restrict__ deg, int* __restrict__ pre, int* __restrict__ bsum, int m) {
  __shared__ int sd[256];
  int t = threadIdx.x;
  int base = blockIdx.x * 2048 + t * 8;
  int v[8], sum = 0;
#pragma unroll
  for (int j = 0; j < 8; ++j) {
    v[j] = (base + j < m) ? deg[base + j] : 0;
    sum += v[j];
  }
  sd[t] = sum;
  __syncthreads();
  for (int off = 1; off < 256; off <<= 1) {
    int x = (t >= off) ? sd[t - off] : 0;
    __syncthreads();
    if (t >= off) sd[t] += x;
    __syncthreads();
  }
  if (t == 255) bsum[blockIdx.x] = sd[255];
  int run = sd[t] - sum;
#pragma unroll
  for (int j = 0; j < 8; ++j) {
    if (base + j < m) pre[base + j] = run;
    run += v[j];
  }
}

__global__ __launch_bounds__(256) void scan2_kernel(int* __restrict__ bsum, int nb) {
  __shared__ int sd[256];
  int t = threadIdx.x;
  int v = (t < nb) ? bsum[t] : 0;
  sd[t] = v;
  __syncthreads();
  for (int off = 1; off < 256; off <<= 1) {
    int x = (t >= off) ? sd[t - off] : 0;
    __syncthreads();
    if (t >= off) sd[t] += x;
    __syncthreads();
  }
  if (t < nb) bsum[t] = sd[t] - v;
}

__global__ void scan3_kernel(int* __restrict__ pre, const int* __restrict__ bsum, int m, int total) {
  int i = blockIdx.x * 256 + threadIdx.x;
  if (i < m) pre[i] += bsum[i >> 11];
  if (i == m) pre[m] = total;
}

__global__ void fill2_kernel(const int* __restrict__ e0s, const int* __restrict__ e0d,
                             const int* __restrict__ e1s, const int* __restrict__ e1d,
                             const int* __restrict__ pre, int* __restrict__ cur,
                             int* __restrict__ csr, int ne, int n) {
  int e = blockIdx.x * 256 + threadIdx.x;
  int s, idx;
  if (e < ne) { idx = e0d[e]; s = e0s[e]; }
  else if (e < 2 * ne) { idx = n + e1d[e - ne]; s = e1s[e - ne]; }
  else return;
  int slot = pre[idx] + atomicAdd(&cur[idx], 1);
  csr[slot] = s;
}

// ---------- per-dst softmax aggregation (max-free), both relations ----------
__global__ __launch_bounds__(256) void agg2_kernel(
    const int* __restrict__ pre, const int* __restrict__ csr,
    const unsigned short* __restrict__ Hb, const float* __restrict__ preb,
    unsigned short* __restrict__ outb, int n) {
  int rel = blockIdx.y;
  int gid = blockIdx.x * 256 + threadIdx.x;
  int node = gid >> 5;
  int lane = gid & 31;
  if (node >= n) return;
  int head = lane >> 2;
  const size_t n8 = (size_t)n * 8;
  const float* a_s = preb + (size_t)(2 * rel) * n8;
  const float* a_d = preb + (size_t)(2 * rel + 1) * n8;
  int beg = pre[rel * n + node], end = pre[rel * n + node + 1];
  float ad = a_d[(size_t)node * 8 + head];
  float s = 0.f;
  float ax = 0.f, ay = 0.f, az = 0.f, aw = 0.f;
  int e = beg;
  for (; e + 1 < end; e += 2) {
    int s0 = csr[e], s1 = csr[e + 1];
    float al0 = a_s[(size_t)s0 * 8 + head] + ad;
    float al1 = a_s[(size_t)s1 * 8 + head] + ad;
    ushort4 h0 = *(const ushort4*)(Hb + (size_t)s0 * 128 + lane * 4);
    ushort4 h1 = *(const ushort4*)(Hb + (size_t)s1 * 128 + lane * 4);
    al0 = (al0 >= 0.f) ? al0 : 0.2f * al0;
    al1 = (al1 >= 0.f) ? al1 : 0.2f * al1;
    float p0 = __expf(al0), p1 = __expf(al1);
    s += p0 + p1;
    ax += p0 * b2f(h0.x) + p1 * b2f(h1.x);
    ay += p0 * b2f(h0.y) + p1 * b2f(h1.y);
    az += p0 * b2f(h0.z) + p1 * b2f(h1.z);
    aw += p0 * b2f(h0.w) + p1 * b2f(h1.w);
  }
  if (e < end) {
    int s0 = csr[e];
    float al0 = a_s[(size_t)s0 * 8 + head] + ad;
    ushort4 h0 = *(const ushort4*)(Hb + (size_t)s0 * 128 + lane * 4);
    al0 = (al0 >= 0.f) ? al0 : 0.2f * al0;
    float p0 = __expf(al0);
    s += p0;
    ax += p0 * b2f(h0.x);
    ay += p0 * b2f(h0.y);
    az += p0 * b2f(h0.z);
    aw += p0 * b2f(h0.w);
  }
  float inv = 1.f / (s + 1e-16f);
  ushort4 o;
  o.x = f2b(fmaxf(ax * inv, 0.f));
  o.y = f2b(fmaxf(ay * inv, 0.f));
  o.z = f2b(fmaxf(az * inv, 0.f));
  o.w = f2b(fmaxf(aw * inv, 0.f));
  *(ushort4*)(outb + (size_t)rel * n * 128 + (size_t)node * 128 + lane * 4) = o;
}

// ---------- semantic score, both relations ----------
__global__ __launch_bounds__(256) void score2_mfma(
    const unsigned short* __restrict__ outb, const unsigned short* __restrict__ Kf,
    const float* __restrict__ kb, const float* __restrict__ q,
    float* __restrict__ sb, int n) {
  __shared__ float red[256];
  const int rel = blockIdx.y;
  const unsigned short* A = outb + (size_t)rel * n * 128;
  const int tid = threadIdx.x;
  const int wid = tid >> 6, lane = tid & 63;
  const int wm = wid >> 1, wn = wid & 1;
  const int row0 = blockIdx.x * 128 + wm * 64;
  const int r = lane & 15, ks = lane >> 4;
  f32x4 acc[4][4] = {};

  const unsigned short* aptr[4];
#pragma unroll
  for (int mi = 0; mi < 4; ++mi) {
    int row = row0 + mi * 16 + r;
    row = row < n ? row : n - 1;
    aptr[mi] = A + (size_t)row * 128 + ks * 8;
  }
  const unsigned short* bptr = Kf + ((size_t)(wn * 4) * 64 + lane) * 8;

  bf16x8 ra[2][4], rb[2][4];
#pragma unroll
  for (int mi = 0; mi < 4; ++mi) ra[0][mi] = *(const bf16x8*)(aptr[mi]);
#pragma unroll
  for (int ni = 0; ni < 4; ++ni) rb[0][ni] = *(const bf16x8*)(bptr + (size_t)ni * 64 * 8);

#pragma unroll
  for (int kt = 0; kt < 4; ++kt) {
    const int cur = kt & 1, nxt = cur ^ 1;
    if (kt < 3) {
#pragma unroll
      for (int mi = 0; mi < 4; ++mi)
        ra[nxt][mi] = *(const bf16x8*)(aptr[mi] + (kt + 1) * 32);
      const unsigned short* bp = bptr + (size_t)(kt + 1) * 8 * 64 * 8;
#pragma unroll
      for (int ni = 0; ni < 4; ++ni)
        rb[nxt][ni] = *(const bf16x8*)(bp + (size_t)ni * 64 * 8);
    }
#pragma unroll
    for (int mi = 0; mi < 4; ++mi)
#pragma unroll
      for (int ni = 0; ni < 4; ++ni)
        acc[mi][ni] = __builtin_amdgcn_mfma_f32_16x16x32_bf16(ra[cur][mi], rb[cur][ni], acc[mi][ni], 0, 0, 0);
  }
  float part = 0.f;
#pragma unroll
  for (int ni = 0; ni < 4; ++ni) {
    const int col = wn * 64 + ni * 16 + r;
    const float kbv = kb[col], qv = q[col];
#pragma unroll
    for (int mi = 0; mi < 4; ++mi) {
#pragma unroll
      for (int i = 0; i < 4; ++i) {
        int row = row0 + mi * 16 + ks * 4 + i;
        if (row < n) part += tanhf(acc[mi][ni][i] + kbv) * qv;
      }
    }
  }
  red[tid] = part;
  __syncthreads();
  for (int off = 128; off > 0; off >>= 1) {
    if (tid < off) red[tid] += red[tid + off];
    __syncthreads();
  }
  if (tid == 0) atomicAdd(&sb[rel], red[0]);
}

__global__ void beta_kernel(float* __restrict__ sb, float invn) {
  if (threadIdx.x == 0 && blockIdx.x == 0) {
    float s0 = sb[0] * invn, s1 = sb[1] * invn;
    float m = fmaxf(s0, s1);
    float e0 = __expf(s0 - m), e1 = __expf(s1 - m);
    float d = e0 + e1;
    sb[2] = e0 / d;
    sb[3] = e1 / d;
  }
}

// ---------- fused output ----------
__global__ __launch_bounds__(256) void final_kernel(
    const unsigned short* __restrict__ outb, const float* __restrict__ sb,
    const float* __restrict__ lw, const float* __restrict__ lb,
    float* __restrict__ out, int n) {
  int gid = blockIdx.x * 256 + threadIdx.x;
  int node = gid >> 5, lane = gid & 31;
  if (node >= n) return;
  float b0 = sb[2], b1 = sb[3];
  const unsigned short* o0 = outb;
  const unsigned short* o1 = outb + (size_t)n * 128;
  ushort4 v0 = *(const ushort4*)(o0 + (size_t)node * 128 + lane * 4);
  ushort4 v1 = *(const ushort4*)(o1 + (size_t)node * 128 + lane * 4);
  float f[4] = {b0 * b2f(v0.x) + b1 * b2f(v1.x), b0 * b2f(v0.y) + b1 * b2f(v1.y),
                b0 * b2f(v0.z) + b1 * b2f(v1.z), b0 * b2f(v0.w) + b1 * b2f(v1.w)};
  float p0 = 0.f, p1 = 0.f, p2 = 0.f;
  int c0 = lane * 4;
#pragma unroll
  for (int j = 0; j < 4; ++j) {
    const float* w = lw + (size_t)(c0 + j) * 3;
    p0 += f[j] * w[0];
    p1 += f[j] * w[1];
    p2 += f[j] * w[2];
  }
#pragma unroll
  for (int off = 16; off > 0; off >>= 1) {
    p0 += __shfl_down(p0, off, 32);
    p1 += __shfl_down(p1, off, 32);
    p2 += __shfl_down(p2, off, 32);
  }
  if (lane == 0) {
    float* d = out + (size_t)node * 3;
    d[0] = p0 + lb[0];
    d[1] = p1 + lb[1];
    d[2] = p2 + lb[2];
  }
}

extern "C" void kernel_launch(void* const* d_in, const int* in_sizes, int n_in,
                              void* d_out, int out_size, void* d_ws, size_t ws_size,
                              hipStream_t stream) {
  const float* x   = (const float*)d_in[0];
  const float* Wp  = (const float*)d_in[1];
  const float* bp  = (const float*)d_in[2];
  const float* as0 = (const float*)d_in[3];
  const float* ad0 = (const float*)d_in[4];
  const float* as1 = (const float*)d_in[5];
  const float* ad1 = (const float*)d_in[6];
  const float* q   = (const float*)d_in[7];
  const float* kw  = (const float*)d_in[8];
  const float* kb  = (const float*)d_in[9];
  const float* lw  = (const float*)d_in[10];
  const float* lb  = (const float*)d_in[11];
  const int* e0s = (const int*)d_in[12];
  const int* e0d = (const int*)d_in[13];
  const int* e1s = (const int*)d_in[14];
  const int* e1d = (const int*)d_in[15];
  const int n  = in_sizes[0] / 256;
  const int ne = in_sizes[12];
  float* out = (float*)d_out;

  char* ws = (char*)d_ws;
  size_t off = 0;
  auto alloc = [&](size_t b) -> char* {
    char* p = ws + off;
    off = (off + b + 255) & ~(size_t)255;
    return p;
  };
  unsigned short* h    = (unsigned short*)alloc((size_t)n * 128 * 2);
  unsigned short* outb = (unsigned short*)alloc((size_t)2 * n * 128 * 2);
  float* preb = (float*)alloc((size_t)4 * n * 8 * 4);
  int* pre    = (int*)alloc((size_t)(2 * n + 1) * 4);
  int* csr    = (int*)alloc((size_t)2 * ne * 4);
  int* deg    = (int*)alloc(((size_t)4 * n + 4) * 4);
  int* cur    = deg + 2 * n;
  float* sb   = (float*)(deg + 4 * n);
  int* bsum   = (int*)alloc(256 * 4);
  unsigned short* Wpf = (unsigned short*)alloc((size_t)4096 * 8 * 2);
  unsigned short* Kwf = (unsigned short*)alloc((size_t)2048 * 8 * 2);

  const int m = 2 * n;
  const int nblk_scan = (m + 2047) / 2048;

  hipMemsetAsync(deg, 0, ((size_t)4 * n + 4) * 4, stream);
  hipLaunchKernelGGL(wconv2_kernel, dim3(24), dim3(256), 0, stream, Wp, kw, Wpf, Kwf);

  const int gproj = (n + 127) / 128;
  hipLaunchKernelGGL(proj_mfma, dim3(gproj), dim3(256), 0, stream,
                     x, Wpf, bp, as0, ad0, as1, ad1, h, preb, n);

  hipLaunchKernelGGL(count2_kernel, dim3((2 * ne + 255) / 256), dim3(256), 0, stream,
                     e0d, e1d, deg, ne, n);
  hipLaunchKernelGGL(scan1_kernel, dim3(nblk_scan), dim3(256), 0, stream, deg, pre, bsum, m);
  hipLaunchKernelGGL(scan2_kernel, dim3(1), dim3(256), 0, stream, bsum, nblk_scan);
  hipLaunchKernelGGL(scan3_kernel, dim3((m + 1 + 255) / 256), dim3(256), 0, stream,
                     pre, bsum, m, 2 * ne);
  hipLaunchKernelGGL(fill2_kernel, dim3((2 * ne + 255) / 256), dim3(256), 0, stream,
                     e0s, e0d, e1s, e1d, pre, cur, csr, ne, n);
  hipLaunchKernelGGL(agg2_kernel, dim3((n * 32 + 255) / 256, 2), dim3(256), 0, stream,
                     pre, csr, h, preb, outb, n);

  hipLaunchKernelGGL(score2_mfma, dim3(gproj, 2), dim3(256), 0, stream, outb, Kwf, kb, q, sb, n);
  hipLaunchKernelGGL(beta_kernel, dim3(1), dim3(64), 0, stream, sb, 1.0f / n);
  hipLaunchKernelGGL(final_kernel, dim3((n * 32 + 255) / 256), dim3(256), 0, stream,
                     outb, sb, lw, lb, out, n);
}

// Round 5
// 377.825 us; speedup vs baseline: 1.8325x; 1.1095x over previous
//
#include <hip/hip_runtime.h>

// ---------------------------------------------------------------------------
// HAN forward on MI355X — round 5.
//  - proj_mfma: coalesced global->reg->bf16->LDS staging (XOR-swizzled),
//    K-loop = ds_read_b128 fragments + L2 B loads + MFMA. LDS reused for
//    C-tile epilogue + fused attention pre-products.
//  - score2_mfma: same LDS-staged structure (bf16 input, padded rows).
//  - agg2 max-free softmax, single CSR build, grid.y=2 fusions kept.
// ---------------------------------------------------------------------------

typedef __attribute__((ext_vector_type(8))) short bf16x8;
typedef __attribute__((ext_vector_type(4))) float f32x4;
typedef __attribute__((ext_vector_type(8))) unsigned short ushort8;

__device__ __forceinline__ unsigned short f2b(float f) {
  union { float f; unsigned u; } v; v.f = f;
  unsigned r = v.u + 0x7fffu + ((v.u >> 16) & 1u);
  return (unsigned short)(r >> 16);
}
__device__ __forceinline__ float b2f(unsigned short u) {
  union { unsigned u; float f; } v; v.u = ((unsigned)u) << 16;
  return v.f;
}

// ---------- pack W[K][128] fp32 -> bf16 MFMA B-fragment order (both mats) ----------
__global__ __launch_bounds__(256) void wconv2_kernel(
    const float* __restrict__ Wp, const float* __restrict__ kw,
    unsigned short* __restrict__ Wpf, unsigned short* __restrict__ Kwf) {
  int t = blockIdx.x * 256 + threadIdx.x;
  const float* W;
  unsigned short* Wf;
  int idx;
  if (t < 4096) { W = Wp; Wf = Wpf; idx = t; }
  else if (t < 6144) { W = kw; Wf = Kwf; idx = t - 4096; }
  else return;
  int lane = idx & 63, nt = (idx >> 6) & 7, kt = idx >> 9;
  int c = lane & 15, ks = lane >> 4;
  int kbase = kt * 32 + ks * 8;
  int col = nt * 16 + c;
  ushort8 o;
#pragma unroll
  for (int j = 0; j < 8; ++j) o[j] = f2b(W[(size_t)(kbase + j) * 128 + col]);
  *(ushort8*)(Wf + (size_t)idx * 8) = o;
}

// ---------- h = X[n,256] @ W + bias (bf16 out) + fused attention pre-products ----------
__global__ __launch_bounds__(256) void proj_mfma(
    const float* __restrict__ X, const unsigned short* __restrict__ Wf,
    const float* __restrict__ bias,
    const float* __restrict__ as0v, const float* __restrict__ ad0v,
    const float* __restrict__ as1v, const float* __restrict__ ad1v,
    unsigned short* __restrict__ Hb, float* __restrict__ preb, int n) {
  __shared__ unsigned short lds[32768];   // 64 KB: A-tile [128][256] bf16, swizzled
  const int tid = threadIdx.x;
  const int wid = tid >> 6, lane = tid & 63;
  const int wm = wid >> 1, wn = wid & 1;
  const int row0 = blockIdx.x * 128;
  const int r = lane & 15, ks = lane >> 4;

  // ---- stage X tile: coalesced fp32 reads -> bf16 -> swizzled LDS ----
  {
    const int srow = tid >> 4;        // 0..15
    const int sc = tid & 15;          // 16-float column block
#pragma unroll
    for (int j = 0; j < 8; ++j) {
      int lrow = j * 16 + srow;
      int grow = row0 + lrow;
      const float4* src = (const float4*)(X + (size_t)(grow < n ? grow : n - 1) * 256 + sc * 16);
      float4 v0 = src[0], v1 = src[1], v2 = src[2], v3 = src[3];
      ushort8 o0, o1;
      o0[0] = f2b(v0.x); o0[1] = f2b(v0.y); o0[2] = f2b(v0.z); o0[3] = f2b(v0.w);
      o0[4] = f2b(v1.x); o0[5] = f2b(v1.y); o0[6] = f2b(v1.z); o0[7] = f2b(v1.w);
      o1[0] = f2b(v2.x); o1[1] = f2b(v2.y); o1[2] = f2b(v2.z); o1[3] = f2b(v2.w);
      o1[4] = f2b(v3.x); o1[5] = f2b(v3.y); o1[6] = f2b(v3.z); o1[7] = f2b(v3.w);
      int sw = lrow & 7;
      *(ushort8*)&lds[lrow * 256 + ((sc * 2 + 0) ^ sw) * 8] = o0;
      *(ushort8*)&lds[lrow * 256 + ((sc * 2 + 1) ^ sw) * 8] = o1;
    }
  }
  __syncthreads();

  // ---- K-loop: LDS A fragments + L2 B fragments -> MFMA ----
  f32x4 acc[4][4] = {};
  const unsigned short* bptr = Wf + ((size_t)(wn * 4) * 64 + lane) * 8;
#pragma unroll
  for (int kt = 0; kt < 8; ++kt) {
    bf16x8 a[4], b[4];
#pragma unroll
    for (int mi = 0; mi < 4; ++mi) {
      int row = wm * 64 + mi * 16 + r;
      a[mi] = *(const bf16x8*)&lds[row * 256 + ((kt * 4 + ks) ^ (row & 7)) * 8];
    }
#pragma unroll
    for (int ni = 0; ni < 4; ++ni)
      b[ni] = *(const bf16x8*)(bptr + ((size_t)kt * 8 + ni) * 64 * 8);
#pragma unroll
    for (int mi = 0; mi < 4; ++mi)
#pragma unroll
      for (int ni = 0; ni < 4; ++ni)
        acc[mi][ni] = __builtin_amdgcn_mfma_f32_16x16x32_bf16(a[mi], b[ni], acc[mi][ni], 0, 0, 0);
  }
  __syncthreads();   // A-tile dead; reuse LDS as C-tile [128][136]

  // ---- stage C tile (with bias) into LDS as bf16 ----
#pragma unroll
  for (int ni = 0; ni < 4; ++ni) {
    const int col = wn * 64 + ni * 16 + r;
    const float bv = bias[col];
#pragma unroll
    for (int mi = 0; mi < 4; ++mi)
#pragma unroll
      for (int i = 0; i < 4; ++i)
        lds[(wm * 64 + mi * 16 + ks * 4 + i) * 136 + col] = f2b(acc[mi][ni][i] + bv);
  }
  __syncthreads();

  // coalesced global store: 2 threads per row, 128B each
  {
    int row = tid >> 1, half = tid & 1;
    int grow = row0 + row;
    if (grow < n) {
      ushort8* dst = (ushort8*)(Hb + (size_t)grow * 128 + half * 64);
#pragma unroll
      for (int j = 0; j < 8; ++j) dst[j] = *(ushort8*)&lds[row * 136 + half * 64 + j * 8];
    }
  }

  // fused pre-products
  const size_t n8 = (size_t)n * 8;
  for (int rh = tid; rh < 1024; rh += 256) {
    int row = rh >> 3, head = rh & 7;
    int node = row0 + row;
    if (node < n) {
      float hv[16];
#pragma unroll
      for (int j = 0; j < 16; ++j) hv[j] = b2f(lds[row * 136 + head * 16 + j]);
      float s0 = 0, d0 = 0, s1 = 0, d1 = 0;
      const float* p0 = as0v + head * 16;
      const float* p1 = ad0v + head * 16;
      const float* p2 = as1v + head * 16;
      const float* p3 = ad1v + head * 16;
#pragma unroll
      for (int j = 0; j < 16; ++j) {
        float v = hv[j];
        s0 += v * p0[j]; d0 += v * p1[j];
        s1 += v * p2[j]; d1 += v * p3[j];
      }
      size_t idx = (size_t)node * 8 + head;
      preb[idx] = s0;
      preb[n8 + idx] = d0;
      preb[2 * n8 + idx] = s1;
      preb[3 * n8 + idx] = d1;
    }
  }
}

// ---------- CSR build (both relations in one pass) ----------
__global__ void count2_kernel(const int* __restrict__ e0d, const int* __restrict__ e1d,
                              int* __restrict__ deg, int ne, int n) {
  int e = blockIdx.x * 256 + threadIdx.x;
  if (e < ne) atomicAdd(&deg[e0d[e]], 1);
  else if (e < 2 * ne) atomicAdd(&deg[n + e1d[e - ne]], 1);
}

__global__ __launch_bounds__(256) void scan1_kernel(
    const int* __restrict__ deg, int* __restrict__ pre, int* __restrict__ bsum, int m) {
  __shared__ int sd[256];
  int t = threadIdx.x;
  int base = blockIdx.x * 2048 + t * 8;
  int v[8], sum = 0;
#pragma unroll
  for (int j = 0; j < 8; ++j) {
    v[j] = (base + j < m) ? deg[base + j] : 0;
    sum += v[j];
  }
  sd[t] = sum;
  __syncthreads();
  for (int off = 1; off < 256; off <<= 1) {
    int x = (t >= off) ? sd[t - off] : 0;
    __syncthreads();
    if (t >= off) sd[t] += x;
    __syncthreads();
  }
  if (t == 255) bsum[blockIdx.x] = sd[255];
  int run = sd[t] - sum;
#pragma unroll
  for (int j = 0; j < 8; ++j) {
    if (base + j < m) pre[base + j] = run;
    run += v[j];
  }
}

__global__ __launch_bounds__(256) void scan2_kernel(int* __restrict__ bsum, int nb) {
  __shared__ int sd[256];
  int t = threadIdx.x;
  int v = (t < nb) ? bsum[t] : 0;
  sd[t] = v;
  __syncthreads();
  for (int off = 1; off < 256; off <<= 1) {
    int x = (t >= off) ? sd[t - off] : 0;
    __syncthreads();
    if (t >= off) sd[t] += x;
    __syncthreads();
  }
  if (t < nb) bsum[t] = sd[t] - v;
}

__global__ void scan3_kernel(int* __restrict__ pre, const int* __restrict__ bsum, int m, int total) {
  int i = blockIdx.x * 256 + threadIdx.x;
  if (i < m) pre[i] += bsum[i >> 11];
  if (i == m) pre[m] = total;
}

__global__ void fill2_kernel(const int* __restrict__ e0s, const int* __restrict__ e0d,
                             const int* __restrict__ e1s, const int* __restrict__ e1d,
                             const int* __restrict__ pre, int* __restrict__ cur,
                             int* __restrict__ csr, int ne, int n) {
  int e = blockIdx.x * 256 + threadIdx.x;
  int s, idx;
  if (e < ne) { idx = e0d[e]; s = e0s[e]; }
  else if (e < 2 * ne) { idx = n + e1d[e - ne]; s = e1s[e - ne]; }
  else return;
  int slot = pre[idx] + atomicAdd(&cur[idx], 1);
  csr[slot] = s;
}

// ---------- per-dst softmax aggregation (max-free), both relations ----------
__global__ __launch_bounds__(256) void agg2_kernel(
    const int* __restrict__ pre, const int* __restrict__ csr,
    const unsigned short* __restrict__ Hb, const float* __restrict__ preb,
    unsigned short* __restrict__ outb, int n) {
  int rel = blockIdx.y;
  int gid = blockIdx.x * 256 + threadIdx.x;
  int node = gid >> 5;
  int lane = gid & 31;
  if (node >= n) return;
  int head = lane >> 2;
  const size_t n8 = (size_t)n * 8;
  const float* a_s = preb + (size_t)(2 * rel) * n8;
  const float* a_d = preb + (size_t)(2 * rel + 1) * n8;
  int beg = pre[rel * n + node], end = pre[rel * n + node + 1];
  float ad = a_d[(size_t)node * 8 + head];
  float s = 0.f;
  float ax = 0.f, ay = 0.f, az = 0.f, aw = 0.f;
  int e = beg;
  for (; e + 1 < end; e += 2) {
    int s0 = csr[e], s1 = csr[e + 1];
    float al0 = a_s[(size_t)s0 * 8 + head] + ad;
    float al1 = a_s[(size_t)s1 * 8 + head] + ad;
    ushort4 h0 = *(const ushort4*)(Hb + (size_t)s0 * 128 + lane * 4);
    ushort4 h1 = *(const ushort4*)(Hb + (size_t)s1 * 128 + lane * 4);
    al0 = (al0 >= 0.f) ? al0 : 0.2f * al0;
    al1 = (al1 >= 0.f) ? al1 : 0.2f * al1;
    float p0 = __expf(al0), p1 = __expf(al1);
    s += p0 + p1;
    ax += p0 * b2f(h0.x) + p1 * b2f(h1.x);
    ay += p0 * b2f(h0.y) + p1 * b2f(h1.y);
    az += p0 * b2f(h0.z) + p1 * b2f(h1.z);
    aw += p0 * b2f(h0.w) + p1 * b2f(h1.w);
  }
  if (e < end) {
    int s0 = csr[e];
    float al0 = a_s[(size_t)s0 * 8 + head] + ad;
    ushort4 h0 = *(const ushort4*)(Hb + (size_t)s0 * 128 + lane * 4);
    al0 = (al0 >= 0.f) ? al0 : 0.2f * al0;
    float p0 = __expf(al0);
    s += p0;
    ax += p0 * b2f(h0.x);
    ay += p0 * b2f(h0.y);
    az += p0 * b2f(h0.z);
    aw += p0 * b2f(h0.w);
  }
  float inv = 1.f / (s + 1e-16f);
  ushort4 o;
  o.x = f2b(fmaxf(ax * inv, 0.f));
  o.y = f2b(fmaxf(ay * inv, 0.f));
  o.z = f2b(fmaxf(az * inv, 0.f));
  o.w = f2b(fmaxf(aw * inv, 0.f));
  *(ushort4*)(outb + (size_t)rel * n * 128 + (size_t)node * 128 + lane * 4) = o;
}

// ---------- semantic score, both relations (LDS-staged A) ----------
__global__ __launch_bounds__(256) void score2_mfma(
    const unsigned short* __restrict__ outb, const unsigned short* __restrict__ Kf,
    const float* __restrict__ kb, const float* __restrict__ q,
    float* __restrict__ sb, int n) {
  __shared__ unsigned short at[128 * 136];   // padded rows: 272B stride
  __shared__ float red[256];
  const int rel = blockIdx.y;
  const unsigned short* A = outb + (size_t)rel * n * 128;
  const int tid = threadIdx.x;
  const int wid = tid >> 6, lane = tid & 63;
  const int wm = wid >> 1, wn = wid & 1;
  const int row0 = blockIdx.x * 128;
  const int r = lane & 15, ks = lane >> 4;

  // stage A tile: coalesced bf16 reads -> padded LDS
  {
    const int srow = tid >> 4;   // 0..15
    const int sc = tid & 15;     // 16B chunk
#pragma unroll
    for (int j = 0; j < 8; ++j) {
      int lrow = j * 16 + srow;
      int grow = row0 + lrow;
      ushort8 v = *(const ushort8*)(A + (size_t)(grow < n ? grow : n - 1) * 128 + sc * 8);
      *(ushort8*)&at[lrow * 136 + sc * 8] = v;
    }
  }
  __syncthreads();

  f32x4 acc[4][4] = {};
  const unsigned short* bptr = Kf + ((size_t)(wn * 4) * 64 + lane) * 8;
#pragma unroll
  for (int kt = 0; kt < 4; ++kt) {
    bf16x8 a[4], b[4];
#pragma unroll
    for (int mi = 0; mi < 4; ++mi) {
      int row = wm * 64 + mi * 16 + r;
      a[mi] = *(const bf16x8*)&at[row * 136 + kt * 32 + ks * 8];
    }
#pragma unroll
    for (int ni = 0; ni < 4; ++ni)
      b[ni] = *(const bf16x8*)(bptr + ((size_t)kt * 8 + ni) * 64 * 8);
#pragma unroll
    for (int mi = 0; mi < 4; ++mi)
#pragma unroll
      for (int ni = 0; ni < 4; ++ni)
        acc[mi][ni] = __builtin_amdgcn_mfma_f32_16x16x32_bf16(a[mi], b[ni], acc[mi][ni], 0, 0, 0);
  }
  float part = 0.f;
#pragma unroll
  for (int ni = 0; ni < 4; ++ni) {
    const int col = wn * 64 + ni * 16 + r;
    const float kbv = kb[col], qv = q[col];
#pragma unroll
    for (int mi = 0; mi < 4; ++mi) {
#pragma unroll
      for (int i = 0; i < 4; ++i) {
        int row = row0 + wm * 64 + mi * 16 + ks * 4 + i;
        if (row < n) part += tanhf(acc[mi][ni][i] + kbv) * qv;
      }
    }
  }
  red[tid] = part;
  __syncthreads();
  for (int off = 128; off > 0; off >>= 1) {
    if (tid < off) red[tid] += red[tid + off];
    __syncthreads();
  }
  if (tid == 0) atomicAdd(&sb[rel], red[0]);
}

__global__ void beta_kernel(float* __restrict__ sb, float invn) {
  if (threadIdx.x == 0 && blockIdx.x == 0) {
    float s0 = sb[0] * invn, s1 = sb[1] * invn;
    float m = fmaxf(s0, s1);
    float e0 = __expf(s0 - m), e1 = __expf(s1 - m);
    float d = e0 + e1;
    sb[2] = e0 / d;
    sb[3] = e1 / d;
  }
}

// ---------- fused output ----------
__global__ __launch_bounds__(256) void final_kernel(
    const unsigned short* __restrict__ outb, const float* __restrict__ sb,
    const float* __restrict__ lw, const float* __restrict__ lb,
    float* __restrict__ out, int n) {
  int gid = blockIdx.x * 256 + threadIdx.x;
  int node = gid >> 5, lane = gid & 31;
  if (node >= n) return;
  float b0 = sb[2], b1 = sb[3];
  const unsigned short* o0 = outb;
  const unsigned short* o1 = outb + (size_t)n * 128;
  ushort4 v0 = *(const ushort4*)(o0 + (size_t)node * 128 + lane * 4);
  ushort4 v1 = *(const ushort4*)(o1 + (size_t)node * 128 + lane * 4);
  float f[4] = {b0 * b2f(v0.x) + b1 * b2f(v1.x), b0 * b2f(v0.y) + b1 * b2f(v1.y),
                b0 * b2f(v0.z) + b1 * b2f(v1.z), b0 * b2f(v0.w) + b1 * b2f(v1.w)};
  float p0 = 0.f, p1 = 0.f, p2 = 0.f;
  int c0 = lane * 4;
#pragma unroll
  for (int j = 0; j < 4; ++j) {
    const float* w = lw + (size_t)(c0 + j) * 3;
    p0 += f[j] * w[0];
    p1 += f[j] * w[1];
    p2 += f[j] * w[2];
  }
#pragma unroll
  for (int off = 16; off > 0; off >>= 1) {
    p0 += __shfl_down(p0, off, 32);
    p1 += __shfl_down(p1, off, 32);
    p2 += __shfl_down(p2, off, 32);
  }
  if (lane == 0) {
    float* d = out + (size_t)node * 3;
    d[0] = p0 + lb[0];
    d[1] = p1 + lb[1];
    d[2] = p2 + lb[2];
  }
}

extern "C" void kernel_launch(void* const* d_in, const int* in_sizes, int n_in,
                              void* d_out, int out_size, void* d_ws, size_t ws_size,
                              hipStream_t stream) {
  const float* x   = (const float*)d_in[0];
  const float* Wp  = (const float*)d_in[1];
  const float* bp  = (const float*)d_in[2];
  const float* as0 = (const float*)d_in[3];
  const float* ad0 = (const float*)d_in[4];
  const float* as1 = (const float*)d_in[5];
  const float* ad1 = (const float*)d_in[6];
  const float* q   = (const float*)d_in[7];
  const float* kw  = (const float*)d_in[8];
  const float* kb  = (const float*)d_in[9];
  const float* lw  = (const float*)d_in[10];
  const float* lb  = (const float*)d_in[11];
  const int* e0s = (const int*)d_in[12];
  const int* e0d = (const int*)d_in[13];
  const int* e1s = (const int*)d_in[14];
  const int* e1d = (const int*)d_in[15];
  const int n  = in_sizes[0] / 256;
  const int ne = in_sizes[12];
  float* out = (float*)d_out;

  char* ws = (char*)d_ws;
  size_t off = 0;
  auto alloc = [&](size_t b) -> char* {
    char* p = ws + off;
    off = (off + b + 255) & ~(size_t)255;
    return p;
  };
  unsigned short* h    = (unsigned short*)alloc((size_t)n * 128 * 2);
  unsigned short* outb = (unsigned short*)alloc((size_t)2 * n * 128 * 2);
  float* preb = (float*)alloc((size_t)4 * n * 8 * 4);
  int* pre    = (int*)alloc((size_t)(2 * n + 1) * 4);
  int* csr    = (int*)alloc((size_t)2 * ne * 4);
  int* deg    = (int*)alloc(((size_t)4 * n + 4) * 4);
  int* cur    = deg + 2 * n;
  float* sb   = (float*)(deg + 4 * n);
  int* bsum   = (int*)alloc(256 * 4);
  unsigned short* Wpf = (unsigned short*)alloc((size_t)4096 * 8 * 2);
  unsigned short* Kwf = (unsigned short*)alloc((size_t)2048 * 8 * 2);

  const int m = 2 * n;
  const int nblk_scan = (m + 2047) / 2048;

  hipMemsetAsync(deg, 0, ((size_t)4 * n + 4) * 4, stream);
  hipLaunchKernelGGL(wconv2_kernel, dim3(24), dim3(256), 0, stream, Wp, kw, Wpf, Kwf);

  const int gproj = (n + 127) / 128;
  hipLaunchKernelGGL(proj_mfma, dim3(gproj), dim3(256), 0, stream,
                     x, Wpf, bp, as0, ad0, as1, ad1, h, preb, n);

  hipLaunchKernelGGL(count2_kernel, dim3((2 * ne + 255) / 256), dim3(256), 0, stream,
                     e0d, e1d, deg, ne, n);
  hipLaunchKernelGGL(scan1_kernel, dim3(nblk_scan), dim3(256), 0, stream, deg, pre, bsum, m);
  hipLaunchKernelGGL(scan2_kernel, dim3(1), dim3(256), 0, stream, bsum, nblk_scan);
  hipLaunchKernelGGL(scan3_kernel, dim3((m + 1 + 255) / 256), dim3(256), 0, stream,
                     pre, bsum, m, 2 * ne);
  hipLaunchKernelGGL(fill2_kernel, dim3((2 * ne + 255) / 256), dim3(256), 0, stream,
                     e0s, e0d, e1s, e1d, pre, cur, csr, ne, n);
  hipLaunchKernelGGL(agg2_kernel, dim3((n * 32 + 255) / 256, 2), dim3(256), 0, stream,
                     pre, csr, h, preb, outb, n);

  hipLaunchKernelGGL(score2_mfma, dim3(gproj, 2), dim3(256), 0, stream, outb, Kwf, kb, q, sb, n);
  hipLaunchKernelGGL(beta_kernel, dim3(1), dim3(64), 0, stream, sb, 1.0f / n);
  hipLaunchKernelGGL(final_kernel, dim3((n * 32 + 255) / 256), dim3(256), 0, stream,
                     outb, sb, lw, lb, out, n);
}

// Round 6
// 361.351 us; speedup vs baseline: 1.9160x; 1.0456x over previous
//
#include <hip/hip_runtime.h>

// ---------------------------------------------------------------------------
// HAN forward on MI355X — round 6.
//  - prep_kernel: fused {X fp32->bf16 stream-convert | edge-count atomics |
//    W fragment pack} via blockIdx role split (1 dispatch).
//  - proj_mfma: A staged via global_load_lds width=16 (linear LDS dest,
//    inverse-swizzled per-lane global src, XOR on ds_read), MFMA K-loop,
//    LDS C-tile epilogue + fused attention pre-products.
//  - score2_mfma: global_load_lds staging, fast tanh, fused out_r@lin_w
//    per-row projection (final reads 6.4MB instead of 102MB).
//  - agg2 max-free softmax, single CSR build, grid.y=2 fusions kept.
// ---------------------------------------------------------------------------

typedef __attribute__((ext_vector_type(8))) short bf16x8;
typedef __attribute__((ext_vector_type(4))) float f32x4;
typedef __attribute__((ext_vector_type(8))) unsigned short ushort8;

__device__ __forceinline__ unsigned short f2b(float f) {
  union { float f; unsigned u; } v; v.f = f;
  unsigned r = v.u + 0x7fffu + ((v.u >> 16) & 1u);
  return (unsigned short)(r >> 16);
}
__device__ __forceinline__ float b2f(unsigned short u) {
  union { unsigned u; float f; } v; v.u = ((unsigned)u) << 16;
  return v.f;
}
__device__ __forceinline__ float fast_tanh(float x) {
  x = fminf(fmaxf(x, -15.f), 15.f);
  float t = __expf(2.f * x);
  return 1.f - 2.f / (t + 1.f);
}
__device__ __forceinline__ void gload_lds16(const unsigned short* g, unsigned short* l) {
  __builtin_amdgcn_global_load_lds(
      (const __attribute__((address_space(1))) unsigned int*)g,
      (__attribute__((address_space(3))) unsigned int*)l, 16, 0, 0);
}

// ---------- prep: conv_x | count2 | wconv2 fused via block role split ----------
__global__ __launch_bounds__(256) void prep_kernel(
    const float* __restrict__ X, unsigned short* __restrict__ xb, int n,
    const int* __restrict__ e0d, const int* __restrict__ e1d,
    int* __restrict__ deg, int ne,
    const float* __restrict__ Wp, const float* __restrict__ kwm,
    unsigned short* __restrict__ Wpf, unsigned short* __restrict__ Kwf) {
  const int tid = threadIdx.x;
  int b = blockIdx.x;
  if (b < 1024) {   // role 1: X fp32 -> bf16 stream convert
    const long total8 = (long)n * 32;
    for (long i = (long)b * 256 + tid; i < total8; i += 1024L * 256) {
      const float4* s = (const float4*)(X + i * 8);
      float4 v0 = s[0], v1 = s[1];
      ushort8 o;
      o[0] = f2b(v0.x); o[1] = f2b(v0.y); o[2] = f2b(v0.z); o[3] = f2b(v0.w);
      o[4] = f2b(v1.x); o[5] = f2b(v1.y); o[6] = f2b(v1.z); o[7] = f2b(v1.w);
      *(ushort8*)(xb + i * 8) = o;
    }
    return;
  }
  b -= 1024;
  const int cb = (2 * ne + 255) >> 8;
  if (b < cb) {     // role 2: degree count (both relations)
    int e = b * 256 + tid;
    if (e < ne) atomicAdd(&deg[e0d[e]], 1);
    else if (e < 2 * ne) atomicAdd(&deg[n + e1d[e - ne]], 1);
    return;
  }
  b -= cb;          // role 3: pack W into MFMA B-fragment order
  int t = b * 256 + tid;
  const float* W; unsigned short* Wf; int idx;
  if (t < 4096) { W = Wp; Wf = Wpf; idx = t; }
  else if (t < 6144) { W = kwm; Wf = Kwf; idx = t - 4096; }
  else return;
  int lane = idx & 63, nt = (idx >> 6) & 7, kt = idx >> 9;
  int c = lane & 15, ks = lane >> 4;
  int kbase = kt * 32 + ks * 8;
  int col = nt * 16 + c;
  ushort8 o;
#pragma unroll
  for (int j = 0; j < 8; ++j) o[j] = f2b(W[(size_t)(kbase + j) * 128 + col]);
  *(ushort8*)(Wf + (size_t)idx * 8) = o;
}

// ---------- h = xb[n,256] @ W + bias (bf16 out) + fused attention pre-products ----------
__global__ __launch_bounds__(256) void proj_mfma(
    const unsigned short* __restrict__ xb, const unsigned short* __restrict__ Wf,
    const float* __restrict__ bias,
    const float* __restrict__ as0v, const float* __restrict__ ad0v,
    const float* __restrict__ as1v, const float* __restrict__ ad1v,
    unsigned short* __restrict__ Hb, float* __restrict__ preb, int n) {
  __shared__ unsigned short ats[32768];   // 64 KB: A-tile [128][256] bf16 (chunk-swizzled)
  const int tid = threadIdx.x;
  const int wid = tid >> 6, lane = tid & 63;
  const int wm = wid >> 1, wn = wid & 1;
  const int row0 = blockIdx.x * 128;
  const int r = lane & 15, ks = lane >> 4;

  // ---- stage A: global_load_lds, linear dest, inverse-swizzled source ----
  {
    unsigned short* dstbase = ats + wid * 8192;    // wave region: 32 rows = 16KB
#pragma unroll
    for (int i = 0; i < 16; ++i) {
      int chunk = i * 64 + lane;                   // 16B chunk within wave region
      int row = wid * 32 + (chunk >> 5);           // 32 chunks (512B) per row
      int c = chunk & 31;
      int grow = row0 + row;
      grow = grow < n ? grow : n - 1;
      const unsigned short* src = xb + (size_t)grow * 256 + ((c ^ (row & 7)) * 8);
      gload_lds16(src, dstbase + i * 512);         // wave-uniform dest + lane*16
    }
  }
  __syncthreads();

  // ---- K-loop: swizzled ds_read A + L2 B fragments -> MFMA ----
  f32x4 acc[4][4] = {};
  const unsigned short* bptr = Wf + ((size_t)(wn * 4) * 64 + lane) * 8;
#pragma unroll
  for (int kt = 0; kt < 8; ++kt) {
    bf16x8 a[4], b[4];
#pragma unroll
    for (int mi = 0; mi < 4; ++mi) {
      int row = wm * 64 + mi * 16 + r;
      a[mi] = *(const bf16x8*)&ats[row * 256 + (((kt * 4 + ks) ^ (row & 7)) * 8)];
    }
#pragma unroll
    for (int ni = 0; ni < 4; ++ni)
      b[ni] = *(const bf16x8*)(bptr + ((size_t)kt * 8 + ni) * 512);
#pragma unroll
    for (int mi = 0; mi < 4; ++mi)
#pragma unroll
      for (int ni = 0; ni < 4; ++ni)
        acc[mi][ni] = __builtin_amdgcn_mfma_f32_16x16x32_bf16(a[mi], b[ni], acc[mi][ni], 0, 0, 0);
  }
  __syncthreads();   // A-tile dead; reuse LDS as C-tile [128][136]

  // ---- stage C tile (with bias) into LDS as bf16 ----
#pragma unroll
  for (int ni = 0; ni < 4; ++ni) {
    const int col = wn * 64 + ni * 16 + r;
    const float bv = bias[col];
#pragma unroll
    for (int mi = 0; mi < 4; ++mi)
#pragma unroll
      for (int i = 0; i < 4; ++i)
        ats[(wm * 64 + mi * 16 + ks * 4 + i) * 136 + col] = f2b(acc[mi][ni][i] + bv);
  }
  __syncthreads();

  // coalesced global store: 2 threads per row, 128B each
  {
    int row = tid >> 1, half = tid & 1;
    int grow = row0 + row;
    if (grow < n) {
      ushort8* dst = (ushort8*)(Hb + (size_t)grow * 128 + half * 64);
#pragma unroll
      for (int j = 0; j < 8; ++j) dst[j] = *(ushort8*)&ats[row * 136 + half * 64 + j * 8];
    }
  }

  // fused pre-products
  const size_t n8 = (size_t)n * 8;
  for (int rh = tid; rh < 1024; rh += 256) {
    int row = rh >> 3, head = rh & 7;
    int node = row0 + row;
    if (node < n) {
      float hv[16];
#pragma unroll
      for (int j = 0; j < 16; ++j) hv[j] = b2f(ats[row * 136 + head * 16 + j]);
      float s0 = 0, d0 = 0, s1 = 0, d1 = 0;
      const float* p0 = as0v + head * 16;
      const float* p1 = ad0v + head * 16;
      const float* p2 = as1v + head * 16;
      const float* p3 = ad1v + head * 16;
#pragma unroll
      for (int j = 0; j < 16; ++j) {
        float v = hv[j];
        s0 += v * p0[j]; d0 += v * p1[j];
        s1 += v * p2[j]; d1 += v * p3[j];
      }
      size_t idx = (size_t)node * 8 + head;
      preb[idx] = s0;
      preb[n8 + idx] = d0;
      preb[2 * n8 + idx] = s1;
      preb[3 * n8 + idx] = d1;
    }
  }
}

// ---------- CSR scans ----------
__global__ __launch_bounds__(256) void scan1_kernel(
    const int* __restrict__ deg, int* __restrict__ pre, int* __restrict__ bsum, int m) {
  __shared__ int sd[256];
  int t = threadIdx.x;
  int base = blockIdx.x * 2048 + t * 8;
  int v[8], sum = 0;
#pragma unroll
  for (int j = 0; j < 8; ++j) {
    v[j] = (base + j < m) ? deg[base + j] : 0;
    sum += v[j];
  }
  sd[t] = sum;
  __syncthreads();
  for (int off = 1; off < 256; off <<= 1) {
    int x = (t >= off) ? sd[t - off] : 0;
    __syncthreads();
    if (t >= off) sd[t] += x;
    __syncthreads();
  }
  if (t == 255) bsum[blockIdx.x] = sd[255];
  int run = sd[t] - sum;
#pragma unroll
  for (int j = 0; j < 8; ++j) {
    if (base + j < m) pre[base + j] = run;
    run += v[j];
  }
}

__global__ __launch_bounds__(256) void scan2_kernel(int* __restrict__ bsum, int nb) {
  __shared__ int sd[256];
  int t = threadIdx.x;
  int v = (t < nb) ? bsum[t] : 0;
  sd[t] = v;
  __syncthreads();
  for (int off = 1; off < 256; off <<= 1) {
    int x = (t >= off) ? sd[t - off] : 0;
    __syncthreads();
    if (t >= off) sd[t] += x;
    __syncthreads();
  }
  if (t < nb) bsum[t] = sd[t] - v;
}

__global__ void scan3_kernel(int* __restrict__ pre, const int* __restrict__ bsum, int m, int total) {
  int i = blockIdx.x * 256 + threadIdx.x;
  if (i < m) pre[i] += bsum[i >> 11];
  if (i == m) pre[m] = total;
}

__global__ void fill2_kernel(const int* __restrict__ e0s, const int* __restrict__ e0d,
                             const int* __restrict__ e1s, const int* __restrict__ e1d,
                             const int* __restrict__ pre, int* __restrict__ cur,
                             int* __restrict__ csr, int ne, int n) {
  int e = blockIdx.x * 256 + threadIdx.x;
  int s, idx;
  if (e < ne) { idx = e0d[e]; s = e0s[e]; }
  else if (e < 2 * ne) { idx = n + e1d[e - ne]; s = e1s[e - ne]; }
  else return;
  int slot = pre[idx] + atomicAdd(&cur[idx], 1);
  csr[slot] = s;
}

// ---------- per-dst softmax aggregation (max-free), both relations ----------
__global__ __launch_bounds__(256) void agg2_kernel(
    const int* __restrict__ pre, const int* __restrict__ csr,
    const unsigned short* __restrict__ Hb, const float* __restrict__ preb,
    unsigned short* __restrict__ outb, int n) {
  int rel = blockIdx.y;
  int gid = blockIdx.x * 256 + threadIdx.x;
  int node = gid >> 5;
  int lane = gid & 31;
  if (node >= n) return;
  int head = lane >> 2;
  const size_t n8 = (size_t)n * 8;
  const float* a_s = preb + (size_t)(2 * rel) * n8;
  const float* a_d = preb + (size_t)(2 * rel + 1) * n8;
  int beg = pre[rel * n + node], end = pre[rel * n + node + 1];
  float ad = a_d[(size_t)node * 8 + head];
  float s = 0.f;
  float ax = 0.f, ay = 0.f, az = 0.f, aw = 0.f;
  int e = beg;
  for (; e + 1 < end; e += 2) {
    int s0 = csr[e], s1 = csr[e + 1];
    float al0 = a_s[(size_t)s0 * 8 + head] + ad;
    float al1 = a_s[(size_t)s1 * 8 + head] + ad;
    ushort4 h0 = *(const ushort4*)(Hb + (size_t)s0 * 128 + lane * 4);
    ushort4 h1 = *(const ushort4*)(Hb + (size_t)s1 * 128 + lane * 4);
    al0 = (al0 >= 0.f) ? al0 : 0.2f * al0;
    al1 = (al1 >= 0.f) ? al1 : 0.2f * al1;
    float p0 = __expf(al0), p1 = __expf(al1);
    s += p0 + p1;
    ax += p0 * b2f(h0.x) + p1 * b2f(h1.x);
    ay += p0 * b2f(h0.y) + p1 * b2f(h1.y);
    az += p0 * b2f(h0.z) + p1 * b2f(h1.z);
    aw += p0 * b2f(h0.w) + p1 * b2f(h1.w);
  }
  if (e < end) {
    int s0 = csr[e];
    float al0 = a_s[(size_t)s0 * 8 + head] + ad;
    ushort4 h0 = *(const ushort4*)(Hb + (size_t)s0 * 128 + lane * 4);
    al0 = (al0 >= 0.f) ? al0 : 0.2f * al0;
    float p0 = __expf(al0);
    s += p0;
    ax += p0 * b2f(h0.x);
    ay += p0 * b2f(h0.y);
    az += p0 * b2f(h0.z);
    aw += p0 * b2f(h0.w);
  }
  float inv = 1.f / (s + 1e-16f);
  ushort4 o;
  o.x = f2b(fmaxf(ax * inv, 0.f));
  o.y = f2b(fmaxf(ay * inv, 0.f));
  o.z = f2b(fmaxf(az * inv, 0.f));
  o.w = f2b(fmaxf(aw * inv, 0.f));
  *(ushort4*)(outb + (size_t)rel * n * 128 + (size_t)node * 128 + lane * 4) = o;
}

// ---------- semantic score + fused out_r @ lin_w, both relations ----------
__global__ __launch_bounds__(256) void score2_mfma(
    const unsigned short* __restrict__ outb, const unsigned short* __restrict__ Kf,
    const float* __restrict__ kb, const float* __restrict__ q,
    const float* __restrict__ lw, float* __restrict__ pout,
    float* __restrict__ sb, int n) {
  __shared__ unsigned short at[16384];   // [128][128] bf16, chunk-swizzled (32KB)
  __shared__ float red[256];
  const int rel = blockIdx.y;
  const unsigned short* A = outb + (size_t)rel * n * 128;
  const int tid = threadIdx.x;
  const int wid = tid >> 6, lane = tid & 63;
  const int wm = wid >> 1, wn = wid & 1;
  const int row0 = blockIdx.x * 128;
  const int r = lane & 15, ks = lane >> 4;

  // stage A tile: global_load_lds, inverse-swizzled source
  {
    unsigned short* dstbase = at + wid * 4096;      // 32 rows = 8KB per wave
#pragma unroll
    for (int i = 0; i < 8; ++i) {
      int chunk = i * 64 + lane;
      int row = wid * 32 + (chunk >> 4);            // 16 chunks (256B) per row
      int c = chunk & 15;
      int grow = row0 + row;
      grow = grow < n ? grow : n - 1;
      const unsigned short* src = A + (size_t)grow * 128 + ((c ^ (row & 7)) * 8);
      gload_lds16(src, dstbase + i * 512);
    }
  }
  __syncthreads();

  f32x4 acc[4][4] = {};
  const unsigned short* bptr = Kf + ((size_t)(wn * 4) * 64 + lane) * 8;
#pragma unroll
  for (int kt = 0; kt < 4; ++kt) {
    bf16x8 a[4], b[4];
#pragma unroll
    for (int mi = 0; mi < 4; ++mi) {
      int row = wm * 64 + mi * 16 + r;
      a[mi] = *(const bf16x8*)&at[row * 128 + (((kt * 4 + ks) ^ (row & 7)) * 8)];
    }
#pragma unroll
    for (int ni = 0; ni < 4; ++ni)
      b[ni] = *(const bf16x8*)(bptr + ((size_t)kt * 8 + ni) * 512);
#pragma unroll
    for (int mi = 0; mi < 4; ++mi)
#pragma unroll
      for (int ni = 0; ni < 4; ++ni)
        acc[mi][ni] = __builtin_amdgcn_mfma_f32_16x16x32_bf16(a[mi], b[ni], acc[mi][ni], 0, 0, 0);
  }

  // fused per-row projection onto lin_w (3 cols) from the staged tile
  if (tid < 128) {
    int node = row0 + tid;
    if (node < n) {
      float p0 = 0.f, p1 = 0.f, p2 = 0.f;
      int s = tid & 7;
#pragma unroll
      for (int c = 0; c < 16; ++c) {
        const unsigned short* rp = &at[tid * 128 + ((c ^ s) * 8)];
#pragma unroll
        for (int j = 0; j < 8; ++j) {
          float v = b2f(rp[j]);
          const float* w = lw + (size_t)(c * 8 + j) * 3;
          p0 += v * w[0]; p1 += v * w[1]; p2 += v * w[2];
        }
      }
      float4 o = make_float4(p0, p1, p2, 0.f);
      *(float4*)(pout + (size_t)node * 8 + rel * 4) = o;
    }
  }

  // tanh(acc + kb) . q partial sum
  float part = 0.f;
#pragma unroll
  for (int ni = 0; ni < 4; ++ni) {
    const int col = wn * 64 + ni * 16 + r;
    const float kbv = kb[col], qv = q[col];
#pragma unroll
    for (int mi = 0; mi < 4; ++mi) {
#pragma unroll
      for (int i = 0; i < 4; ++i) {
        int row = row0 + wm * 64 + mi * 16 + ks * 4 + i;
        if (row < n) part += fast_tanh(acc[mi][ni][i] + kbv) * qv;
      }
    }
  }
  red[tid] = part;
  __syncthreads();
  for (int off = 128; off > 0; off >>= 1) {
    if (tid < off) red[tid] += red[tid + off];
    __syncthreads();
  }
  if (tid == 0) atomicAdd(&sb[rel], red[0]);
}

__global__ void beta_kernel(float* __restrict__ sb, float invn) {
  if (threadIdx.x == 0 && blockIdx.x == 0) {
    float s0 = sb[0] * invn, s1 = sb[1] * invn;
    float m = fmaxf(s0, s1);
    float e0 = __expf(s0 - m), e1 = __expf(s1 - m);
    float d = e0 + e1;
    sb[2] = e0 / d;
    sb[3] = e1 / d;
  }
}

// ---------- final: out = b0*p0 + b1*p1 + lb ----------
__global__ __launch_bounds__(256) void final2_kernel(
    const float* __restrict__ pout, const float* __restrict__ sb,
    const float* __restrict__ lb, float* __restrict__ out, int n) {
  int node = blockIdx.x * 256 + threadIdx.x;
  if (node >= n) return;
  float b0 = sb[2], b1 = sb[3];
  const float4* p = (const float4*)(pout + (size_t)node * 8);
  float4 pa = p[0], pb = p[1];
  float* d = out + (size_t)node * 3;
  d[0] = b0 * pa.x + b1 * pb.x + lb[0];
  d[1] = b0 * pa.y + b1 * pb.y + lb[1];
  d[2] = b0 * pa.z + b1 * pb.z + lb[2];
}

extern "C" void kernel_launch(void* const* d_in, const int* in_sizes, int n_in,
                              void* d_out, int out_size, void* d_ws, size_t ws_size,
                              hipStream_t stream) {
  const float* x   = (const float*)d_in[0];
  const float* Wp  = (const float*)d_in[1];
  const float* bp  = (const float*)d_in[2];
  const float* as0 = (const float*)d_in[3];
  const float* ad0 = (const float*)d_in[4];
  const float* as1 = (const float*)d_in[5];
  const float* ad1 = (const float*)d_in[6];
  const float* q   = (const float*)d_in[7];
  const float* kw  = (const float*)d_in[8];
  const float* kb  = (const float*)d_in[9];
  const float* lw  = (const float*)d_in[10];
  const float* lb  = (const float*)d_in[11];
  const int* e0s = (const int*)d_in[12];
  const int* e0d = (const int*)d_in[13];
  const int* e1s = (const int*)d_in[14];
  const int* e1d = (const int*)d_in[15];
  const int n  = in_sizes[0] / 256;
  const int ne = in_sizes[12];
  float* out = (float*)d_out;

  char* ws = (char*)d_ws;
  size_t off = 0;
  auto alloc = [&](size_t b) -> char* {
    char* p = ws + off;
    off = (off + b + 255) & ~(size_t)255;
    return p;
  };
  unsigned short* xb   = (unsigned short*)alloc((size_t)n * 256 * 2);
  unsigned short* h    = (unsigned short*)alloc((size_t)n * 128 * 2);
  unsigned short* outb = (unsigned short*)alloc((size_t)2 * n * 128 * 2);
  float* preb = (float*)alloc((size_t)4 * n * 8 * 4);
  float* pout = (float*)alloc((size_t)n * 8 * 4);
  int* pre    = (int*)alloc((size_t)(2 * n + 1) * 4);
  int* csr    = (int*)alloc((size_t)2 * ne * 4);
  int* deg    = (int*)alloc(((size_t)4 * n + 4) * 4);   // deg(2n) | cur(2n) | sb(4)
  int* cur    = deg + 2 * n;
  float* sb   = (float*)(deg + 4 * n);
  int* bsum   = (int*)alloc(256 * 4);
  unsigned short* Wpf = (unsigned short*)alloc((size_t)4096 * 8 * 2);
  unsigned short* Kwf = (unsigned short*)alloc((size_t)2048 * 8 * 2);

  const int m = 2 * n;
  const int nblk_scan = (m + 2047) / 2048;
  const int cnt_blks = (2 * ne + 255) / 256;

  hipMemsetAsync(deg, 0, ((size_t)4 * n + 4) * 4, stream);
  hipLaunchKernelGGL(prep_kernel, dim3(1024 + cnt_blks + 24), dim3(256), 0, stream,
                     x, xb, n, e0d, e1d, deg, ne, Wp, kw, Wpf, Kwf);

  const int gproj = (n + 127) / 128;
  hipLaunchKernelGGL(proj_mfma, dim3(gproj), dim3(256), 0, stream,
                     xb, Wpf, bp, as0, ad0, as1, ad1, h, preb, n);

  hipLaunchKernelGGL(scan1_kernel, dim3(nblk_scan), dim3(256), 0, stream, deg, pre, bsum, m);
  hipLaunchKernelGGL(scan2_kernel, dim3(1), dim3(256), 0, stream, bsum, nblk_scan);
  hipLaunchKernelGGL(scan3_kernel, dim3((m + 1 + 255) / 256), dim3(256), 0, stream,
                     pre, bsum, m, 2 * ne);
  hipLaunchKernelGGL(fill2_kernel, dim3((2 * ne + 255) / 256), dim3(256), 0, stream,
                     e0s, e0d, e1s, e1d, pre, cur, csr, ne, n);
  hipLaunchKernelGGL(agg2_kernel, dim3((n * 32 + 255) / 256, 2), dim3(256), 0, stream,
                     pre, csr, h, preb, outb, n);

  hipLaunchKernelGGL(score2_mfma, dim3(gproj, 2), dim3(256), 0, stream,
                     outb, Kwf, kb, q, lw, pout, sb, n);
  hipLaunchKernelGGL(beta_kernel, dim3(1), dim3(64), 0, stream, sb, 1.0f / n);
  hipLaunchKernelGGL(final2_kernel, dim3((n + 255) / 256), dim3(256), 0, stream,
                     pout, sb, lb, out, n);
}

// Round 7
// 350.511 us; speedup vs baseline: 1.9753x; 1.0309x over previous
//
#include <hip/hip_runtime.h>

// ---------------------------------------------------------------------------
// HAN forward on MI355X — round 7.
//  - prep_lite: {edge-count atomics | W fragment pack} (xb conversion pass
//    eliminated).
//  - proj_mfma: stages fp32 X directly via global_load_lds (64KB LDS, XOR
//    involution swizzle), fp32->bf16 convert at fragment read, BM=64 pure
//    GEMM + LDS C-tile epilogue + fused attention pre-products.
//  - agg2: 8 lanes/node (lane == head), 8 nodes/wave -> 4x wave throughput,
//    max-free softmax, 2-edge unroll.
//  - score2_mfma: global_load_lds staging + fused out_r@lin_w projection.
// ---------------------------------------------------------------------------

typedef __attribute__((ext_vector_type(8))) short bf16x8;
typedef __attribute__((ext_vector_type(4))) float f32x4;
typedef __attribute__((ext_vector_type(8))) unsigned short ushort8;

__device__ __forceinline__ unsigned short f2b(float f) {
  union { float f; unsigned u; } v; v.f = f;
  unsigned r = v.u + 0x7fffu + ((v.u >> 16) & 1u);
  return (unsigned short)(r >> 16);
}
__device__ __forceinline__ float b2f(unsigned short u) {
  union { unsigned u; float f; } v; v.u = ((unsigned)u) << 16;
  return v.f;
}
__device__ __forceinline__ float fast_tanh(float x) {
  x = fminf(fmaxf(x, -15.f), 15.f);
  float t = __expf(2.f * x);
  return 1.f - 2.f / (t + 1.f);
}
__device__ __forceinline__ void gload_lds16(const void* g, void* l) {
  __builtin_amdgcn_global_load_lds(
      (const __attribute__((address_space(1))) unsigned int*)g,
      (__attribute__((address_space(3))) unsigned int*)l, 16, 0, 0);
}

// ---------- prep_lite: edge count | W fragment pack ----------
__global__ __launch_bounds__(256) void prep_lite(
    const int* __restrict__ e0d, const int* __restrict__ e1d,
    int* __restrict__ deg, int ne, int n,
    const float* __restrict__ Wp, const float* __restrict__ kwm,
    unsigned short* __restrict__ Wpf, unsigned short* __restrict__ Kwf) {
  const int tid = threadIdx.x;
  int b = blockIdx.x;
  const int cb = (2 * ne + 255) >> 8;
  if (b < cb) {     // role 1: degree count (both relations)
    int e = b * 256 + tid;
    if (e < ne) atomicAdd(&deg[e0d[e]], 1);
    else if (e < 2 * ne) atomicAdd(&deg[n + e1d[e - ne]], 1);
    return;
  }
  b -= cb;          // role 2: pack W into MFMA B-fragment order
  int t = b * 256 + tid;
  const float* W; unsigned short* Wf; int idx;
  if (t < 4096) { W = Wp; Wf = Wpf; idx = t; }
  else if (t < 6144) { W = kwm; Wf = Kwf; idx = t - 4096; }
  else return;
  int lane = idx & 63, nt = (idx >> 6) & 7, kt = idx >> 9;
  int c = lane & 15, ks = lane >> 4;
  int kbase = kt * 32 + ks * 8;
  int col = nt * 16 + c;
  ushort8 o;
#pragma unroll
  for (int j = 0; j < 8; ++j) o[j] = f2b(W[(size_t)(kbase + j) * 128 + col]);
  *(ushort8*)(Wf + (size_t)idx * 8) = o;
}

// ---------- h = X[n,256] @ W + bias (bf16 out) + fused pre-products ----------
// BM=64: A-tile fp32 [64][256] = 64KB LDS, chunk-XOR swizzled.
__global__ __launch_bounds__(256) void proj_mfma(
    const float* __restrict__ X, const unsigned short* __restrict__ Wf,
    const float* __restrict__ bias,
    const float* __restrict__ as0v, const float* __restrict__ ad0v,
    const float* __restrict__ as1v, const float* __restrict__ ad1v,
    unsigned short* __restrict__ Hb, float* __restrict__ preb, int n) {
  __shared__ float atsf[16384];   // 64 KB
  const int tid = threadIdx.x;
  const int wid = tid >> 6, lane = tid & 63;
  const int wm = wid >> 1, wn = wid & 1;
  const int row0 = blockIdx.x * 64;
  const int r = lane & 15, ks = lane >> 4;

  // ---- stage A: global_load_lds (1KB row per issue), inverse-swizzled src ----
  {
    float* dstbase = atsf + wid * 16 * 256;
#pragma unroll
    for (int i = 0; i < 16; ++i) {
      int row = wid * 16 + i;
      int grow = row0 + row;
      grow = grow < n ? grow : n - 1;
      const float* src = X + (size_t)grow * 256 + ((lane ^ (i & 7)) * 4);
      gload_lds16(src, dstbase + i * 256);
    }
  }
  __syncthreads();

  // ---- K-loop: swizzled ds_read fp32 -> bf16 fragments + L2 B -> MFMA ----
  f32x4 acc[2][4] = {};
  const unsigned short* bptr = Wf + ((size_t)(wn * 4) * 64 + lane) * 8;
  const int sw = r & 7;
#pragma unroll
  for (int kt = 0; kt < 8; ++kt) {
    const int c0 = kt * 8 + ks * 2;
    bf16x8 a[2], b[4];
#pragma unroll
    for (int mi = 0; mi < 2; ++mi) {
      const float* lrow = atsf + (wm * 32 + mi * 16 + r) * 256;
      float4 f0 = *(const float4*)(lrow + ((c0 ^ sw) * 4));
      float4 f1 = *(const float4*)(lrow + (((c0 + 1) ^ sw) * 4));
      bf16x8 v;
      v[0] = (short)f2b(f0.x); v[1] = (short)f2b(f0.y);
      v[2] = (short)f2b(f0.z); v[3] = (short)f2b(f0.w);
      v[4] = (short)f2b(f1.x); v[5] = (short)f2b(f1.y);
      v[6] = (short)f2b(f1.z); v[7] = (short)f2b(f1.w);
      a[mi] = v;
    }
#pragma unroll
    for (int ni = 0; ni < 4; ++ni)
      b[ni] = *(const bf16x8*)(bptr + ((size_t)kt * 8 + ni) * 512);
#pragma unroll
    for (int mi = 0; mi < 2; ++mi)
#pragma unroll
      for (int ni = 0; ni < 4; ++ni)
        acc[mi][ni] = __builtin_amdgcn_mfma_f32_16x16x32_bf16(a[mi], b[ni], acc[mi][ni], 0, 0, 0);
  }
  __syncthreads();   // A-tile dead; reuse LDS as C-tile [64][136] bf16

  unsigned short* ct = (unsigned short*)atsf;
#pragma unroll
  for (int ni = 0; ni < 4; ++ni) {
    const int col = wn * 64 + ni * 16 + r;
    const float bv = bias[col];
#pragma unroll
    for (int mi = 0; mi < 2; ++mi)
#pragma unroll
      for (int i = 0; i < 4; ++i)
        ct[(wm * 32 + mi * 16 + ks * 4 + i) * 136 + col] = f2b(acc[mi][ni][i] + bv);
  }
  __syncthreads();

  // coalesced global store: 4 threads per row, 64B each
  {
    int row = tid >> 2, qq = tid & 3;
    int grow = row0 + row;
    if (grow < n) {
      ushort8* dst = (ushort8*)(Hb + (size_t)grow * 128 + qq * 32);
#pragma unroll
      for (int j = 0; j < 4; ++j) dst[j] = *(ushort8*)&ct[row * 136 + qq * 32 + j * 8];
    }
  }

  // fused pre-products: a_s/a_d for both relations (64 rows x 8 heads)
  const size_t n8 = (size_t)n * 8;
  for (int rh = tid; rh < 512; rh += 256) {
    int row = rh >> 3, head = rh & 7;
    int node = row0 + row;
    if (node < n) {
      float hv[16];
#pragma unroll
      for (int j = 0; j < 16; ++j) hv[j] = b2f(ct[row * 136 + head * 16 + j]);
      float s0 = 0, d0 = 0, s1 = 0, d1 = 0;
      const float* p0 = as0v + head * 16;
      const float* p1 = ad0v + head * 16;
      const float* p2 = as1v + head * 16;
      const float* p3 = ad1v + head * 16;
#pragma unroll
      for (int j = 0; j < 16; ++j) {
        float v = hv[j];
        s0 += v * p0[j]; d0 += v * p1[j];
        s1 += v * p2[j]; d1 += v * p3[j];
      }
      size_t idx = (size_t)node * 8 + head;
      preb[idx] = s0;
      preb[n8 + idx] = d0;
      preb[2 * n8 + idx] = s1;
      preb[3 * n8 + idx] = d1;
    }
  }
}

// ---------- CSR scans ----------
__global__ __launch_bounds__(256) void scan1_kernel(
    const int* __restrict__ deg, int* __restrict__ pre, int* __restrict__ bsum, int m) {
  __shared__ int sd[256];
  int t = threadIdx.x;
  int base = blockIdx.x * 2048 + t * 8;
  int v[8], sum = 0;
#pragma unroll
  for (int j = 0; j < 8; ++j) {
    v[j] = (base + j < m) ? deg[base + j] : 0;
    sum += v[j];
  }
  sd[t] = sum;
  __syncthreads();
  for (int off = 1; off < 256; off <<= 1) {
    int x = (t >= off) ? sd[t - off] : 0;
    __syncthreads();
    if (t >= off) sd[t] += x;
    __syncthreads();
  }
  if (t == 255) bsum[blockIdx.x] = sd[255];
  int run = sd[t] - sum;
#pragma unroll
  for (int j = 0; j < 8; ++j) {
    if (base + j < m) pre[base + j] = run;
    run += v[j];
  }
}

__global__ __launch_bounds__(256) void scan2_kernel(int* __restrict__ bsum, int nb) {
  __shared__ int sd[256];
  int t = threadIdx.x;
  int v = (t < nb) ? bsum[t] : 0;
  sd[t] = v;
  __syncthreads();
  for (int off = 1; off < 256; off <<= 1) {
    int x = (t >= off) ? sd[t - off] : 0;
    __syncthreads();
    if (t >= off) sd[t] += x;
    __syncthreads();
  }
  if (t < nb) bsum[t] = sd[t] - v;
}

__global__ void scan3_kernel(int* __restrict__ pre, const int* __restrict__ bsum, int m, int total) {
  int i = blockIdx.x * 256 + threadIdx.x;
  if (i < m) pre[i] += bsum[i >> 11];
  if (i == m) pre[m] = total;
}

__global__ void fill2_kernel(const int* __restrict__ e0s, const int* __restrict__ e0d,
                             const int* __restrict__ e1s, const int* __restrict__ e1d,
                             const int* __restrict__ pre, int* __restrict__ cur,
                             int* __restrict__ csr, int ne, int n) {
  int e = blockIdx.x * 256 + threadIdx.x;
  int s, idx;
  if (e < ne) { idx = e0d[e]; s = e0s[e]; }
  else if (e < 2 * ne) { idx = n + e1d[e - ne]; s = e1s[e - ne]; }
  else return;
  int slot = pre[idx] + atomicAdd(&cur[idx], 1);
  csr[slot] = s;
}

// ---------- per-dst softmax aggregation: 8 lanes/node (lane == head) ----------
__global__ __launch_bounds__(256) void agg2_kernel(
    const int* __restrict__ pre, const int* __restrict__ csr,
    const unsigned short* __restrict__ Hb, const float* __restrict__ preb,
    unsigned short* __restrict__ outb, int n) {
  int rel = blockIdx.y;
  int gid = blockIdx.x * 256 + threadIdx.x;
  int node = gid >> 3;
  int lane = gid & 7;          // head index; owns dims lane*16..lane*16+15
  if (node >= n) return;
  const size_t n8 = (size_t)n * 8;
  const float* a_s = preb + (size_t)(2 * rel) * n8;
  const float* a_d = preb + (size_t)(2 * rel + 1) * n8;
  int beg = pre[rel * n + node], end = pre[rel * n + node + 1];
  float ad = a_d[(size_t)node * 8 + lane];
  float s = 0.f;
  float acc[16] = {};
  int e = beg;
  for (; e + 1 < end; e += 2) {
    int s0 = csr[e], s1 = csr[e + 1];
    float al0 = a_s[(size_t)s0 * 8 + lane] + ad;
    float al1 = a_s[(size_t)s1 * 8 + lane] + ad;
    const ushort8* h0p = (const ushort8*)(Hb + (size_t)s0 * 128 + lane * 16);
    const ushort8* h1p = (const ushort8*)(Hb + (size_t)s1 * 128 + lane * 16);
    ushort8 h0a = h0p[0], h0b = h0p[1];
    ushort8 h1a = h1p[0], h1b = h1p[1];
    al0 = (al0 >= 0.f) ? al0 : 0.2f * al0;
    al1 = (al1 >= 0.f) ? al1 : 0.2f * al1;
    float p0 = __expf(al0), p1 = __expf(al1);
    s += p0 + p1;
#pragma unroll
    for (int j = 0; j < 8; ++j) {
      acc[j]     += p0 * b2f(h0a[j]) + p1 * b2f(h1a[j]);
      acc[8 + j] += p0 * b2f(h0b[j]) + p1 * b2f(h1b[j]);
    }
  }
  if (e < end) {
    int s0 = csr[e];
    float al0 = a_s[(size_t)s0 * 8 + lane] + ad;
    const ushort8* h0p = (const ushort8*)(Hb + (size_t)s0 * 128 + lane * 16);
    ushort8 h0a = h0p[0], h0b = h0p[1];
    al0 = (al0 >= 0.f) ? al0 : 0.2f * al0;
    float p0 = __expf(al0);
    s += p0;
#pragma unroll
    for (int j = 0; j < 8; ++j) {
      acc[j]     += p0 * b2f(h0a[j]);
      acc[8 + j] += p0 * b2f(h0b[j]);
    }
  }
  float inv = 1.f / (s + 1e-16f);
  ushort8 o0, o1;
#pragma unroll
  for (int j = 0; j < 8; ++j) {
    o0[j] = f2b(fmaxf(acc[j] * inv, 0.f));
    o1[j] = f2b(fmaxf(acc[8 + j] * inv, 0.f));
  }
  ushort8* dst = (ushort8*)(outb + (size_t)rel * n * 128 + (size_t)node * 128 + lane * 16);
  dst[0] = o0;
  dst[1] = o1;
}

// ---------- semantic score + fused out_r @ lin_w, both relations ----------
__global__ __launch_bounds__(256) void score2_mfma(
    const unsigned short* __restrict__ outb, const unsigned short* __restrict__ Kf,
    const float* __restrict__ kb, const float* __restrict__ q,
    const float* __restrict__ lw, float* __restrict__ pout,
    float* __restrict__ sb, int n) {
  __shared__ unsigned short at[16384];   // [128][128] bf16, chunk-swizzled (32KB)
  __shared__ float red[256];
  const int rel = blockIdx.y;
  const unsigned short* A = outb + (size_t)rel * n * 128;
  const int tid = threadIdx.x;
  const int wid = tid >> 6, lane = tid & 63;
  const int wm = wid >> 1, wn = wid & 1;
  const int row0 = blockIdx.x * 128;
  const int r = lane & 15, ks = lane >> 4;

  // stage A tile: global_load_lds, inverse-swizzled source
  {
    unsigned short* dstbase = at + wid * 4096;
#pragma unroll
    for (int i = 0; i < 8; ++i) {
      int chunk = i * 64 + lane;
      int row = wid * 32 + (chunk >> 4);
      int c = chunk & 15;
      int grow = row0 + row;
      grow = grow < n ? grow : n - 1;
      const unsigned short* src = A + (size_t)grow * 128 + ((c ^ (row & 7)) * 8);
      gload_lds16(src, dstbase + i * 512);
    }
  }
  __syncthreads();

  f32x4 acc[4][4] = {};
  const unsigned short* bptr = Kf + ((size_t)(wn * 4) * 64 + lane) * 8;
#pragma unroll
  for (int kt = 0; kt < 4; ++kt) {
    bf16x8 a[4], b[4];
#pragma unroll
    for (int mi = 0; mi < 4; ++mi) {
      int row = wm * 64 + mi * 16 + r;
      a[mi] = *(const bf16x8*)&at[row * 128 + (((kt * 4 + ks) ^ (row & 7)) * 8)];
    }
#pragma unroll
    for (int ni = 0; ni < 4; ++ni)
      b[ni] = *(const bf16x8*)(bptr + ((size_t)kt * 8 + ni) * 512);
#pragma unroll
    for (int mi = 0; mi < 4; ++mi)
#pragma unroll
      for (int ni = 0; ni < 4; ++ni)
        acc[mi][ni] = __builtin_amdgcn_mfma_f32_16x16x32_bf16(a[mi], b[ni], acc[mi][ni], 0, 0, 0);
  }

  // fused per-row projection onto lin_w (3 cols) from the staged tile
  if (tid < 128) {
    int node = row0 + tid;
    if (node < n) {
      float p0 = 0.f, p1 = 0.f, p2 = 0.f;
      int s = tid & 7;
#pragma unroll
      for (int c = 0; c < 16; ++c) {
        const unsigned short* rp = &at[tid * 128 + ((c ^ s) * 8)];
#pragma unroll
        for (int j = 0; j < 8; ++j) {
          float v = b2f(rp[j]);
          const float* w = lw + (size_t)(c * 8 + j) * 3;
          p0 += v * w[0]; p1 += v * w[1]; p2 += v * w[2];
        }
      }
      float4 o = make_float4(p0, p1, p2, 0.f);
      *(float4*)(pout + (size_t)node * 8 + rel * 4) = o;
    }
  }

  // tanh(acc + kb) . q partial sum
  float part = 0.f;
#pragma unroll
  for (int ni = 0; ni < 4; ++ni) {
    const int col = wn * 64 + ni * 16 + r;
    const float kbv = kb[col], qv = q[col];
#pragma unroll
    for (int mi = 0; mi < 4; ++mi) {
#pragma unroll
      for (int i = 0; i < 4; ++i) {
        int row = row0 + wm * 64 + mi * 16 + ks * 4 + i;
        if (row < n) part += fast_tanh(acc[mi][ni][i] + kbv) * qv;
      }
    }
  }
  red[tid] = part;
  __syncthreads();
  for (int off = 128; off > 0; off >>= 1) {
    if (tid < off) red[tid] += red[tid + off];
    __syncthreads();
  }
  if (tid == 0) atomicAdd(&sb[rel], red[0]);
}

__global__ void beta_kernel(float* __restrict__ sb, float invn) {
  if (threadIdx.x == 0 && blockIdx.x == 0) {
    float s0 = sb[0] * invn, s1 = sb[1] * invn;
    float m = fmaxf(s0, s1);
    float e0 = __expf(s0 - m), e1 = __expf(s1 - m);
    float d = e0 + e1;
    sb[2] = e0 / d;
    sb[3] = e1 / d;
  }
}

// ---------- final: out = b0*p0 + b1*p1 + lb ----------
__global__ __launch_bounds__(256) void final2_kernel(
    const float* __restrict__ pout, const float* __restrict__ sb,
    const float* __restrict__ lb, float* __restrict__ out, int n) {
  int node = blockIdx.x * 256 + threadIdx.x;
  if (node >= n) return;
  float b0 = sb[2], b1 = sb[3];
  const float4* p = (const float4*)(pout + (size_t)node * 8);
  float4 pa = p[0], pb = p[1];
  float* d = out + (size_t)node * 3;
  d[0] = b0 * pa.x + b1 * pb.x + lb[0];
  d[1] = b0 * pa.y + b1 * pb.y + lb[1];
  d[2] = b0 * pa.z + b1 * pb.z + lb[2];
}

extern "C" void kernel_launch(void* const* d_in, const int* in_sizes, int n_in,
                              void* d_out, int out_size, void* d_ws, size_t ws_size,
                              hipStream_t stream) {
  const float* x   = (const float*)d_in[0];
  const float* Wp  = (const float*)d_in[1];
  const float* bp  = (const float*)d_in[2];
  const float* as0 = (const float*)d_in[3];
  const float* ad0 = (const float*)d_in[4];
  const float* as1 = (const float*)d_in[5];
  const float* ad1 = (const float*)d_in[6];
  const float* q   = (const float*)d_in[7];
  const float* kw  = (const float*)d_in[8];
  const float* kb  = (const float*)d_in[9];
  const float* lw  = (const float*)d_in[10];
  const float* lb  = (const float*)d_in[11];
  const int* e0s = (const int*)d_in[12];
  const int* e0d = (const int*)d_in[13];
  const int* e1s = (const int*)d_in[14];
  const int* e1d = (const int*)d_in[15];
  const int n  = in_sizes[0] / 256;
  const int ne = in_sizes[12];
  float* out = (float*)d_out;

  char* ws = (char*)d_ws;
  size_t off = 0;
  auto alloc = [&](size_t b) -> char* {
    char* p = ws + off;
    off = (off + b + 255) & ~(size_t)255;
    return p;
  };
  unsigned short* h    = (unsigned short*)alloc((size_t)n * 128 * 2);
  unsigned short* outb = (unsigned short*)alloc((size_t)2 * n * 128 * 2);
  float* preb = (float*)alloc((size_t)4 * n * 8 * 4);
  float* pout = (float*)alloc((size_t)n * 8 * 4);
  int* pre    = (int*)alloc((size_t)(2 * n + 1) * 4);
  int* csr    = (int*)alloc((size_t)2 * ne * 4);
  int* deg    = (int*)alloc(((size_t)4 * n + 4) * 4);   // deg(2n) | cur(2n) | sb(4)
  int* cur    = deg + 2 * n;
  float* sb   = (float*)(deg + 4 * n);
  int* bsum   = (int*)alloc(256 * 4);
  unsigned short* Wpf = (unsigned short*)alloc((size_t)4096 * 8 * 2);
  unsigned short* Kwf = (unsigned short*)alloc((size_t)2048 * 8 * 2);

  const int m = 2 * n;
  const int nblk_scan = (m + 2047) / 2048;
  const int cnt_blks = (2 * ne + 255) / 256;

  hipMemsetAsync(deg, 0, ((size_t)4 * n + 4) * 4, stream);
  hipLaunchKernelGGL(prep_lite, dim3(cnt_blks + 24), dim3(256), 0, stream,
                     e0d, e1d, deg, ne, n, Wp, kw, Wpf, Kwf);

  const int gproj = (n + 63) / 64;
  hipLaunchKernelGGL(proj_mfma, dim3(gproj), dim3(256), 0, stream,
                     x, Wpf, bp, as0, ad0, as1, ad1, h, preb, n);

  hipLaunchKernelGGL(scan1_kernel, dim3(nblk_scan), dim3(256), 0, stream, deg, pre, bsum, m);
  hipLaunchKernelGGL(scan2_kernel, dim3(1), dim3(256), 0, stream, bsum, nblk_scan);
  hipLaunchKernelGGL(scan3_kernel, dim3((m + 1 + 255) / 256), dim3(256), 0, stream,
                     pre, bsum, m, 2 * ne);
  hipLaunchKernelGGL(fill2_kernel, dim3((2 * ne + 255) / 256), dim3(256), 0, stream,
                     e0s, e0d, e1s, e1d, pre, cur, csr, ne, n);
  hipLaunchKernelGGL(agg2_kernel, dim3((n * 8 + 255) / 256, 2), dim3(256), 0, stream,
                     pre, csr, h, preb, outb, n);

  hipLaunchKernelGGL(score2_mfma, dim3((n + 127) / 128, 2), dim3(256), 0, stream,
                     outb, Kwf, kb, q, lw, pout, sb, n);
  hipLaunchKernelGGL(beta_kernel, dim3(1), dim3(64), 0, stream, sb, 1.0f / n);
  hipLaunchKernelGGL(final2_kernel, dim3((n + 255) / 256), dim3(256), 0, stream,
                     pout, sb, lb, out, n);
}

// Round 8
// 335.823 us; speedup vs baseline: 2.0617x; 1.0437x over previous
//
#include <hip/hip_runtime.h>

// ---------------------------------------------------------------------------
// HAN forward on MI355X — round 8.
//  - proj_mfma: BM=64, BK=64 DOUBLE-BUFFERED global_load_lds pipeline
//    (2x16KB LDS -> 5 blocks/CU), stage(s+1) issued before compute(s),
//    one barrier per step (T3 minimum recipe). fp32->bf16 at fragment read.
//    LDS C-tile epilogue + fused attention pre-products.
//  - agg2: 8 lanes/node (lane == head), max-free softmax, 2-edge unroll.
//  - score2_mfma: global_load_lds staging + fused out_r@lin_w projection.
//  - prep_lite {edge count | W pack}, single CSR build, grid.y=2 fusions.
// ---------------------------------------------------------------------------

typedef __attribute__((ext_vector_type(8))) short bf16x8;
typedef __attribute__((ext_vector_type(4))) float f32x4;
typedef __attribute__((ext_vector_type(8))) unsigned short ushort8;

__device__ __forceinline__ unsigned short f2b(float f) {
  union { float f; unsigned u; } v; v.f = f;
  unsigned r = v.u + 0x7fffu + ((v.u >> 16) & 1u);
  return (unsigned short)(r >> 16);
}
__device__ __forceinline__ float b2f(unsigned short u) {
  union { unsigned u; float f; } v; v.u = ((unsigned)u) << 16;
  return v.f;
}
__device__ __forceinline__ float fast_tanh(float x) {
  x = fminf(fmaxf(x, -15.f), 15.f);
  float t = __expf(2.f * x);
  return 1.f - 2.f / (t + 1.f);
}
__device__ __forceinline__ void gload_lds16(const void* g, void* l) {
  __builtin_amdgcn_global_load_lds(
      (const __attribute__((address_space(1))) unsigned int*)g,
      (__attribute__((address_space(3))) unsigned int*)l, 16, 0, 0);
}

// ---------- prep_lite: edge count | W fragment pack ----------
__global__ __launch_bounds__(256) void prep_lite(
    const int* __restrict__ e0d, const int* __restrict__ e1d,
    int* __restrict__ deg, int ne, int n,
    const float* __restrict__ Wp, const float* __restrict__ kwm,
    unsigned short* __restrict__ Wpf, unsigned short* __restrict__ Kwf) {
  const int tid = threadIdx.x;
  int b = blockIdx.x;
  const int cb = (2 * ne + 255) >> 8;
  if (b < cb) {
    int e = b * 256 + tid;
    if (e < ne) atomicAdd(&deg[e0d[e]], 1);
    else if (e < 2 * ne) atomicAdd(&deg[n + e1d[e - ne]], 1);
    return;
  }
  b -= cb;
  int t = b * 256 + tid;
  const float* W; unsigned short* Wf; int idx;
  if (t < 4096) { W = Wp; Wf = Wpf; idx = t; }
  else if (t < 6144) { W = kwm; Wf = Kwf; idx = t - 4096; }
  else return;
  int lane = idx & 63, nt = (idx >> 6) & 7, kt = idx >> 9;
  int c = lane & 15, ks = lane >> 4;
  int kbase = kt * 32 + ks * 8;
  int col = nt * 16 + c;
  ushort8 o;
#pragma unroll
  for (int j = 0; j < 8; ++j) o[j] = f2b(W[(size_t)(kbase + j) * 128 + col]);
  *(ushort8*)(Wf + (size_t)idx * 8) = o;
}

// ---------- h = X[n,256] @ W + bias (bf16 out) + fused pre-products ----------
// BM=64, BK=64: fp32 A sub-tile [64][64] = 16KB, double-buffered (32KB LDS).
__global__ __launch_bounds__(256) void proj_mfma(
    const float* __restrict__ X, const unsigned short* __restrict__ Wf,
    const float* __restrict__ bias,
    const float* __restrict__ as0v, const float* __restrict__ ad0v,
    const float* __restrict__ as1v, const float* __restrict__ ad1v,
    unsigned short* __restrict__ Hb, float* __restrict__ preb, int n) {
  __shared__ float buf[2][4096];   // 2 x 16KB
  const int tid = threadIdx.x;
  const int wid = tid >> 6, lane = tid & 63;
  const int wm = wid >> 1, wn = wid & 1;
  const int row0 = blockIdx.x * 64;
  const int r = lane & 15, ks = lane >> 4;

  f32x4 acc[2][4] = {};
  const unsigned short* bptr = Wf + ((size_t)(wn * 4) * 64 + lane) * 8;

  // stage step s (cols s*64..s*64+63) into buf[b]; dest linear, src inverse-swz
#define STAGE(b, s)                                                            \
  {                                                                            \
    _Pragma("unroll")                                                          \
    for (int i = 0; i < 4; ++i) {                                              \
      int rloc = wid * 16 + i * 4 + ks;                                        \
      int grow = row0 + rloc;                                                  \
      grow = grow < n ? grow : n - 1;                                          \
      const float* src =                                                       \
          X + (size_t)grow * 256 + (s) * 64 + ((r ^ (rloc & 7)) << 2);         \
      gload_lds16(src, &buf[b][(wid * 16 + i * 4) * 64]);                      \
    }                                                                          \
  }

#define COMPUTE(b, s)                                                          \
  {                                                                            \
    _Pragma("unroll")                                                          \
    for (int kt = 0; kt < 2; ++kt) {                                           \
      bf16x8 a[2], bb[4];                                                      \
      _Pragma("unroll")                                                        \
      for (int mi = 0; mi < 2; ++mi) {                                         \
        int rr = wm * 32 + mi * 16 + r;                                        \
        const float* lrow = &buf[b][rr * 64];                                  \
        int c0 = kt * 8 + ks * 2;                                              \
        int sw = rr & 7;                                                       \
        float4 f0 = *(const float4*)(lrow + ((c0 ^ sw) * 4));                  \
        float4 f1 = *(const float4*)(lrow + (((c0 + 1) ^ sw) * 4));            \
        bf16x8 v;                                                              \
        v[0] = (short)f2b(f0.x); v[1] = (short)f2b(f0.y);                      \
        v[2] = (short)f2b(f0.z); v[3] = (short)f2b(f0.w);                      \
        v[4] = (short)f2b(f1.x); v[5] = (short)f2b(f1.y);                      \
        v[6] = (short)f2b(f1.z); v[7] = (short)f2b(f1.w);                      \
        a[mi] = v;                                                             \
      }                                                                        \
      _Pragma("unroll")                                                        \
      for (int ni = 0; ni < 4; ++ni)                                           \
        bb[ni] = *(const bf16x8*)(bptr + (((size_t)(s) * 2 + kt) * 8 + ni) * 512); \
      _Pragma("unroll")                                                        \
      for (int mi = 0; mi < 2; ++mi)                                           \
        _Pragma("unroll")                                                      \
        for (int ni = 0; ni < 4; ++ni)                                         \
          acc[mi][ni] = __builtin_amdgcn_mfma_f32_16x16x32_bf16(               \
              a[mi], bb[ni], acc[mi][ni], 0, 0, 0);                            \
    }                                                                          \
  }

  STAGE(0, 0);
  __syncthreads();
  // s=0: stage next, compute cur
  STAGE(1, 1); COMPUTE(0, 0); __syncthreads();
  STAGE(0, 2); COMPUTE(1, 1); __syncthreads();
  STAGE(1, 3); COMPUTE(0, 2); __syncthreads();
  COMPUTE(1, 3);
  __syncthreads();   // buffers dead; reuse LDS as C-tile [64][136] bf16
#undef STAGE
#undef COMPUTE

  unsigned short* ct = (unsigned short*)&buf[0][0];
#pragma unroll
  for (int ni = 0; ni < 4; ++ni) {
    const int col = wn * 64 + ni * 16 + r;
    const float bv = bias[col];
#pragma unroll
    for (int mi = 0; mi < 2; ++mi)
#pragma unroll
      for (int i = 0; i < 4; ++i)
        ct[(wm * 32 + mi * 16 + ks * 4 + i) * 136 + col] = f2b(acc[mi][ni][i] + bv);
  }
  __syncthreads();

  // coalesced global store: 4 threads per row, 64B each
  {
    int row = tid >> 2, qq = tid & 3;
    int grow = row0 + row;
    if (grow < n) {
      ushort8* dst = (ushort8*)(Hb + (size_t)grow * 128 + qq * 32);
#pragma unroll
      for (int j = 0; j < 4; ++j) dst[j] = *(ushort8*)&ct[row * 136 + qq * 32 + j * 8];
    }
  }

  // fused pre-products: a_s/a_d for both relations (64 rows x 8 heads)
  const size_t n8 = (size_t)n * 8;
  for (int rh = tid; rh < 512; rh += 256) {
    int row = rh >> 3, head = rh & 7;
    int node = row0 + row;
    if (node < n) {
      float hv[16];
#pragma unroll
      for (int j = 0; j < 16; ++j) hv[j] = b2f(ct[row * 136 + head * 16 + j]);
      float s0 = 0, d0 = 0, s1 = 0, d1 = 0;
      const float* p0 = as0v + head * 16;
      const float* p1 = ad0v + head * 16;
      const float* p2 = as1v + head * 16;
      const float* p3 = ad1v + head * 16;
#pragma unroll
      for (int j = 0; j < 16; ++j) {
        float v = hv[j];
        s0 += v * p0[j]; d0 += v * p1[j];
        s1 += v * p2[j]; d1 += v * p3[j];
      }
      size_t idx = (size_t)node * 8 + head;
      preb[idx] = s0;
      preb[n8 + idx] = d0;
      preb[2 * n8 + idx] = s1;
      preb[3 * n8 + idx] = d1;
    }
  }
}

// ---------- CSR scans ----------
__global__ __launch_bounds__(256) void scan1_kernel(
    const int* __restrict__ deg, int* __restrict__ pre, int* __restrict__ bsum, int m) {
  __shared__ int sd[256];
  int t = threadIdx.x;
  int base = blockIdx.x * 2048 + t * 8;
  int v[8], sum = 0;
#pragma unroll
  for (int j = 0; j < 8; ++j) {
    v[j] = (base + j < m) ? deg[base + j] : 0;
    sum += v[j];
  }
  sd[t] = sum;
  __syncthreads();
  for (int off = 1; off < 256; off <<= 1) {
    int x = (t >= off) ? sd[t - off] : 0;
    __syncthreads();
    if (t >= off) sd[t] += x;
    __syncthreads();
  }
  if (t == 255) bsum[blockIdx.x] = sd[255];
  int run = sd[t] - sum;
#pragma unroll
  for (int j = 0; j < 8; ++j) {
    if (base + j < m) pre[base + j] = run;
    run += v[j];
  }
}

__global__ __launch_bounds__(256) void scan2_kernel(int* __restrict__ bsum, int nb) {
  __shared__ int sd[256];
  int t = threadIdx.x;
  int v = (t < nb) ? bsum[t] : 0;
  sd[t] = v;
  __syncthreads();
  for (int off = 1; off < 256; off <<= 1) {
    int x = (t >= off) ? sd[t - off] : 0;
    __syncthreads();
    if (t >= off) sd[t] += x;
    __syncthreads();
  }
  if (t < nb) bsum[t] = sd[t] - v;
}

__global__ void scan3_kernel(int* __restrict__ pre, const int* __restrict__ bsum, int m, int total) {
  int i = blockIdx.x * 256 + threadIdx.x;
  if (i < m) pre[i] += bsum[i >> 11];
  if (i == m) pre[m] = total;
}

__global__ void fill2_kernel(const int* __restrict__ e0s, const int* __restrict__ e0d,
                             const int* __restrict__ e1s, const int* __restrict__ e1d,
                             const int* __restrict__ pre, int* __restrict__ cur,
                             int* __restrict__ csr, int ne, int n) {
  int e = blockIdx.x * 256 + threadIdx.x;
  int s, idx;
  if (e < ne) { idx = e0d[e]; s = e0s[e]; }
  else if (e < 2 * ne) { idx = n + e1d[e - ne]; s = e1s[e - ne]; }
  else return;
  int slot = pre[idx] + atomicAdd(&cur[idx], 1);
  csr[slot] = s;
}

// ---------- per-dst softmax aggregation: 8 lanes/node (lane == head) ----------
__global__ __launch_bounds__(256) void agg2_kernel(
    const int* __restrict__ pre, const int* __restrict__ csr,
    const unsigned short* __restrict__ Hb, const float* __restrict__ preb,
    unsigned short* __restrict__ outb, int n) {
  int rel = blockIdx.y;
  int gid = blockIdx.x * 256 + threadIdx.x;
  int node = gid >> 3;
  int lane = gid & 7;
  if (node >= n) return;
  const size_t n8 = (size_t)n * 8;
  const float* a_s = preb + (size_t)(2 * rel) * n8;
  const float* a_d = preb + (size_t)(2 * rel + 1) * n8;
  int beg = pre[rel * n + node], end = pre[rel * n + node + 1];
  float ad = a_d[(size_t)node * 8 + lane];
  float s = 0.f;
  float acc[16] = {};
  int e = beg;
  for (; e + 1 < end; e += 2) {
    int s0 = csr[e], s1 = csr[e + 1];
    float al0 = a_s[(size_t)s0 * 8 + lane] + ad;
    float al1 = a_s[(size_t)s1 * 8 + lane] + ad;
    const ushort8* h0p = (const ushort8*)(Hb + (size_t)s0 * 128 + lane * 16);
    const ushort8* h1p = (const ushort8*)(Hb + (size_t)s1 * 128 + lane * 16);
    ushort8 h0a = h0p[0], h0b = h0p[1];
    ushort8 h1a = h1p[0], h1b = h1p[1];
    al0 = (al0 >= 0.f) ? al0 : 0.2f * al0;
    al1 = (al1 >= 0.f) ? al1 : 0.2f * al1;
    float p0 = __expf(al0), p1 = __expf(al1);
    s += p0 + p1;
#pragma unroll
    for (int j = 0; j < 8; ++j) {
      acc[j]     += p0 * b2f(h0a[j]) + p1 * b2f(h1a[j]);
      acc[8 + j] += p0 * b2f(h0b[j]) + p1 * b2f(h1b[j]);
    }
  }
  if (e < end) {
    int s0 = csr[e];
    float al0 = a_s[(size_t)s0 * 8 + lane] + ad;
    const ushort8* h0p = (const ushort8*)(Hb + (size_t)s0 * 128 + lane * 16);
    ushort8 h0a = h0p[0], h0b = h0p[1];
    al0 = (al0 >= 0.f) ? al0 : 0.2f * al0;
    float p0 = __expf(al0);
    s += p0;
#pragma unroll
    for (int j = 0; j < 8; ++j) {
      acc[j]     += p0 * b2f(h0a[j]);
      acc[8 + j] += p0 * b2f(h0b[j]);
    }
  }
  float inv = 1.f / (s + 1e-16f);
  ushort8 o0, o1;
#pragma unroll
  for (int j = 0; j < 8; ++j) {
    o0[j] = f2b(fmaxf(acc[j] * inv, 0.f));
    o1[j] = f2b(fmaxf(acc[8 + j] * inv, 0.f));
  }
  ushort8* dst = (ushort8*)(outb + (size_t)rel * n * 128 + (size_t)node * 128 + lane * 16);
  dst[0] = o0;
  dst[1] = o1;
}

// ---------- semantic score + fused out_r @ lin_w, both relations ----------
__global__ __launch_bounds__(256) void score2_mfma(
    const unsigned short* __restrict__ outb, const unsigned short* __restrict__ Kf,
    const float* __restrict__ kb, const float* __restrict__ q,
    const float* __restrict__ lw, float* __restrict__ pout,
    float* __restrict__ sb, int n) {
  __shared__ unsigned short at[16384];
  __shared__ float red[256];
  const int rel = blockIdx.y;
  const unsigned short* A = outb + (size_t)rel * n * 128;
  const int tid = threadIdx.x;
  const int wid = tid >> 6, lane = tid & 63;
  const int wm = wid >> 1, wn = wid & 1;
  const int row0 = blockIdx.x * 128;
  const int r = lane & 15, ks = lane >> 4;

  {
    unsigned short* dstbase = at + wid * 4096;
#pragma unroll
    for (int i = 0; i < 8; ++i) {
      int chunk = i * 64 + lane;
      int row = wid * 32 + (chunk >> 4);
      int c = chunk & 15;
      int grow = row0 + row;
      grow = grow < n ? grow : n - 1;
      const unsigned short* src = A + (size_t)grow * 128 + ((c ^ (row & 7)) * 8);
      gload_lds16(src, dstbase + i * 512);
    }
  }
  __syncthreads();

  f32x4 acc[4][4] = {};
  const unsigned short* bptr = Kf + ((size_t)(wn * 4) * 64 + lane) * 8;
#pragma unroll
  for (int kt = 0; kt < 4; ++kt) {
    bf16x8 a[4], b[4];
#pragma unroll
    for (int mi = 0; mi < 4; ++mi) {
      int row = wm * 64 + mi * 16 + r;
      a[mi] = *(const bf16x8*)&at[row * 128 + (((kt * 4 + ks) ^ (row & 7)) * 8)];
    }
#pragma unroll
    for (int ni = 0; ni < 4; ++ni)
      b[ni] = *(const bf16x8*)(bptr + ((size_t)kt * 8 + ni) * 512);
#pragma unroll
    for (int mi = 0; mi < 4; ++mi)
#pragma unroll
      for (int ni = 0; ni < 4; ++ni)
        acc[mi][ni] = __builtin_amdgcn_mfma_f32_16x16x32_bf16(a[mi], b[ni], acc[mi][ni], 0, 0, 0);
  }

  if (tid < 128) {
    int node = row0 + tid;
    if (node < n) {
      float p0 = 0.f, p1 = 0.f, p2 = 0.f;
      int s = tid & 7;
#pragma unroll
      for (int c = 0; c < 16; ++c) {
        const unsigned short* rp = &at[tid * 128 + ((c ^ s) * 8)];
#pragma unroll
        for (int j = 0; j < 8; ++j) {
          float v = b2f(rp[j]);
          const float* w = lw + (size_t)(c * 8 + j) * 3;
          p0 += v * w[0]; p1 += v * w[1]; p2 += v * w[2];
        }
      }
      float4 o = make_float4(p0, p1, p2, 0.f);
      *(float4*)(pout + (size_t)node * 8 + rel * 4) = o;
    }
  }

  float part = 0.f;
#pragma unroll
  for (int ni = 0; ni < 4; ++ni) {
    const int col = wn * 64 + ni * 16 + r;
    const float kbv = kb[col], qv = q[col];
#pragma unroll
    for (int mi = 0; mi < 4; ++mi) {
#pragma unroll
      for (int i = 0; i < 4; ++i) {
        int row = row0 + wm * 64 + mi * 16 + ks * 4 + i;
        if (row < n) part += fast_tanh(acc[mi][ni][i] + kbv) * qv;
      }
    }
  }
  red[tid] = part;
  __syncthreads();
  for (int off = 128; off > 0; off >>= 1) {
    if (tid < off) red[tid] += red[tid + off];
    __syncthreads();
  }
  if (tid == 0) atomicAdd(&sb[rel], red[0]);
}

__global__ void beta_kernel(float* __restrict__ sb, float invn) {
  if (threadIdx.x == 0 && blockIdx.x == 0) {
    float s0 = sb[0] * invn, s1 = sb[1] * invn;
    float m = fmaxf(s0, s1);
    float e0 = __expf(s0 - m), e1 = __expf(s1 - m);
    float d = e0 + e1;
    sb[2] = e0 / d;
    sb[3] = e1 / d;
  }
}

__global__ __launch_bounds__(256) void final2_kernel(
    const float* __restrict__ pout, const float* __restrict__ sb,
    const float* __restrict__ lb, float* __restrict__ out, int n) {
  int node = blockIdx.x * 256 + threadIdx.x;
  if (node >= n) return;
  float b0 = sb[2], b1 = sb[3];
  const float4* p = (const float4*)(pout + (size_t)node * 8);
  float4 pa = p[0], pb = p[1];
  float* d = out + (size_t)node * 3;
  d[0] = b0 * pa.x + b1 * pb.x + lb[0];
  d[1] = b0 * pa.y + b1 * pb.y + lb[1];
  d[2] = b0 * pa.z + b1 * pb.z + lb[2];
}

extern "C" void kernel_launch(void* const* d_in, const int* in_sizes, int n_in,
                              void* d_out, int out_size, void* d_ws, size_t ws_size,
                              hipStream_t stream) {
  const float* x   = (const float*)d_in[0];
  const float* Wp  = (const float*)d_in[1];
  const float* bp  = (const float*)d_in[2];
  const float* as0 = (const float*)d_in[3];
  const float* ad0 = (const float*)d_in[4];
  const float* as1 = (const float*)d_in[5];
  const float* ad1 = (const float*)d_in[6];
  const float* q   = (const float*)d_in[7];
  const float* kw  = (const float*)d_in[8];
  const float* kb  = (const float*)d_in[9];
  const float* lw  = (const float*)d_in[10];
  const float* lb  = (const float*)d_in[11];
  const int* e0s = (const int*)d_in[12];
  const int* e0d = (const int*)d_in[13];
  const int* e1s = (const int*)d_in[14];
  const int* e1d = (const int*)d_in[15];
  const int n  = in_sizes[0] / 256;
  const int ne = in_sizes[12];
  float* out = (float*)d_out;

  char* ws = (char*)d_ws;
  size_t off = 0;
  auto alloc = [&](size_t b) -> char* {
    char* p = ws + off;
    off = (off + b + 255) & ~(size_t)255;
    return p;
  };
  unsigned short* h    = (unsigned short*)alloc((size_t)n * 128 * 2);
  unsigned short* outb = (unsigned short*)alloc((size_t)2 * n * 128 * 2);
  float* preb = (float*)alloc((size_t)4 * n * 8 * 4);
  float* pout = (float*)alloc((size_t)n * 8 * 4);
  int* pre    = (int*)alloc((size_t)(2 * n + 1) * 4);
  int* csr    = (int*)alloc((size_t)2 * ne * 4);
  int* deg    = (int*)alloc(((size_t)4 * n + 4) * 4);
  int* cur    = deg + 2 * n;
  float* sb   = (float*)(deg + 4 * n);
  int* bsum   = (int*)alloc(256 * 4);
  unsigned short* Wpf = (unsigned short*)alloc((size_t)4096 * 8 * 2);
  unsigned short* Kwf = (unsigned short*)alloc((size_t)2048 * 8 * 2);

  const int m = 2 * n;
  const int nblk_scan = (m + 2047) / 2048;
  const int cnt_blks = (2 * ne + 255) / 256;

  hipMemsetAsync(deg, 0, ((size_t)4 * n + 4) * 4, stream);
  hipLaunchKernelGGL(prep_lite, dim3(cnt_blks + 24), dim3(256), 0, stream,
                     e0d, e1d, deg, ne, n, Wp, kw, Wpf, Kwf);

  const int gproj = (n + 63) / 64;
  hipLaunchKernelGGL(proj_mfma, dim3(gproj), dim3(256), 0, stream,
                     x, Wpf, bp, as0, ad0, as1, ad1, h, preb, n);

  hipLaunchKernelGGL(scan1_kernel, dim3(nblk_scan), dim3(256), 0, stream, deg, pre, bsum, m);
  hipLaunchKernelGGL(scan2_kernel, dim3(1), dim3(256), 0, stream, bsum, nblk_scan);
  hipLaunchKernelGGL(scan3_kernel, dim3((m + 1 + 255) / 256), dim3(256), 0, stream,
                     pre, bsum, m, 2 * ne);
  hipLaunchKernelGGL(fill2_kernel, dim3((2 * ne + 255) / 256), dim3(256), 0, stream,
                     e0s, e0d, e1s, e1d, pre, cur, csr, ne, n);
  hipLaunchKernelGGL(agg2_kernel, dim3((n * 8 + 255) / 256, 2), dim3(256), 0, stream,
                     pre, csr, h, preb, outb, n);

  hipLaunchKernelGGL(score2_mfma, dim3((n + 127) / 128, 2), dim3(256), 0, stream,
                     outb, Kwf, kb, q, lw, pout, sb, n);
  hipLaunchKernelGGL(beta_kernel, dim3(1), dim3(64), 0, stream, sb, 1.0f / n);
  hipLaunchKernelGGL(final2_kernel, dim3((n + 255) / 256), dim3(256), 0, stream,
                     pout, sb, lb, out, n);
}